// Round 12
// baseline (411.832 us; speedup 1.0000x reference)
//
#include <hip/hip_runtime.h>
#include <hip/hip_bf16.h>
#include <cstdint>

#define T_  4096
#define H_  1024
#define E_  16
#define MI_ 512
#define SI_ 2048
#define TK_ 8192   // T_ * K(=2)

typedef __bf16 bf16;
typedef bf16  bf16x8 __attribute__((ext_vector_type(8)));
typedef bf16  bf16x4 __attribute__((ext_vector_type(4)));
typedef float f32x4  __attribute__((ext_vector_type(4)));

// async global->LDS, 16B per lane. LDS dest = wave-uniform base + lane*16.
__device__ __forceinline__ void gload16(const bf16* g, bf16* lds) {
    __builtin_amdgcn_global_load_lds(
        (const __attribute__((address_space(1))) void*)(uintptr_t)(const void*)g,
        (__attribute__((address_space(3))) void*)(uintptr_t)(void*)lds,
        16, 0, 0);
}

#define SYNC_LGKM0 do { asm volatile("s_waitcnt lgkmcnt(0)" ::: "memory"); \
                        __builtin_amdgcn_s_barrier(); } while (0)
#define SYNC_VM(N) do { asm volatile("s_waitcnt vmcnt(" #N ")" ::: "memory"); \
                        __builtin_amdgcn_s_barrier(); } while (0)

// ---------------- all 5 weight transposes, one launch: fp32 [R][C] -> bf16 [C][R] ----------------
__global__ void k_transpose_all(
    const float* __restrict__ wgu, const float* __restrict__ wdn,
    const float* __restrict__ wsg, const float* __restrict__ wsu, const float* __restrict__ wsd,
    bf16* __restrict__ ogu, bf16* __restrict__ odn,
    bf16* __restrict__ osg, bf16* __restrict__ osu, bf16* __restrict__ osd)
{
    __shared__ float tile[32][33];
    int id = blockIdx.x;
    const float* src; bf16* dst; int R, C, bx, by;
    if (id < 16384) {              // wgu: 16 x [1024][1024]
        int s = id >> 10, r = id & 1023;
        src = wgu + (size_t)s * 1048576; dst = ogu + (size_t)s * 1048576;
        R = 1024; C = 1024; bx = r & 31; by = r >> 5;
    } else if (id < 24576) {       // wdn: 16 x [512][1024]
        int k = id - 16384; int s = k >> 9, r = k & 511;
        src = wdn + (size_t)s * 524288; dst = odn + (size_t)s * 524288;
        R = 512; C = 1024; bx = r & 31; by = r >> 5;
    } else if (id < 26624) {       // wsg: [1024][2048]
        int r = id - 24576;
        src = wsg; dst = osg; R = 1024; C = 2048; bx = r & 63; by = r >> 6;
    } else if (id < 28672) {       // wsu: [1024][2048]
        int r = id - 26624;
        src = wsu; dst = osu; R = 1024; C = 2048; bx = r & 63; by = r >> 6;
    } else {                       // wsd: [2048][1024]
        int r = id - 28672;
        src = wsd; dst = osd; R = 2048; C = 1024; bx = r & 31; by = r >> 5;
    }
    int c = bx * 32 + threadIdx.x;
    #pragma unroll
    for (int i = 0; i < 4; i++) {
        int r_ = by * 32 + threadIdx.y + i * 8;
        tile[threadIdx.y + i * 8][threadIdx.x] = src[(size_t)r_ * C + c];
    }
    __syncthreads();
    int rr = by * 32 + threadIdx.x;
    #pragma unroll
    for (int i = 0; i < 4; i++) {
        int cc = bx * 32 + threadIdx.y + i * 8;
        dst[(size_t)cc * R + rr] = (bf16)tile[threadIdx.x][threadIdx.y + i * 8];
    }
}

// ---------------- router + x->bf16 convert fused. NO atomics. ----------------
__global__ __launch_bounds__(256) void k_router(
    const float* __restrict__ x, const float* __restrict__ rw,
    const float* __restrict__ segw, float* __restrict__ logits_out,
    int* __restrict__ top_i, float* __restrict__ top_w,
    float* __restrict__ gate_scalar, bf16* __restrict__ xb)
{
    int wid = threadIdx.x >> 6, lane = threadIdx.x & 63;
    int t = blockIdx.x * 4 + wid;
    const float* xr = x + (size_t)t * H_;
    bf16* xbr = xb + (size_t)t * H_;
    float acc[E_];
    #pragma unroll
    for (int e = 0; e < E_; e++) acc[e] = 0.f;
    float accg = 0.f;
    for (int j = 0; j < H_ / 64; j++) {
        int h = j * 64 + lane;
        float xv = xr[h];
        xbr[h] = (bf16)xv;                    // fused convert
        const float4* wrow = reinterpret_cast<const float4*>(rw + (size_t)h * E_);
        #pragma unroll
        for (int q = 0; q < 4; q++) {
            float4 w4 = wrow[q];
            acc[q*4+0] += xv * w4.x; acc[q*4+1] += xv * w4.y;
            acc[q*4+2] += xv * w4.z; acc[q*4+3] += xv * w4.w;
        }
        accg += xv * segw[h];
    }
    #pragma unroll
    for (int off = 32; off >= 1; off >>= 1) {
        #pragma unroll
        for (int e = 0; e < E_; e++) acc[e] += __shfl_xor(acc[e], off);
        accg += __shfl_xor(accg, off);
    }
    if (lane == 0) {
        float* lo = logits_out + (size_t)t * E_;
        #pragma unroll
        for (int e = 0; e < E_; e++) lo[e] = acc[e];
        int i0 = 0; float l0 = acc[0];
        #pragma unroll
        for (int e = 1; e < E_; e++) if (acc[e] > l0) { l0 = acc[e]; i0 = e; }
        int i1 = -1; float l1 = -1e30f;
        #pragma unroll
        for (int e = 0; e < E_; e++) if (e != i0 && acc[e] > l1) { l1 = acc[e]; i1 = e; }
        float w0 = 1.f / (1.f + expf(l1 - l0));
        top_i[t*2] = i0; top_i[t*2+1] = i1;
        top_w[t*2] = w0; top_w[t*2+1] = 1.f - w0;
        gate_scalar[t] = 1.f / (1.f + expf(-accg));
    }
}

// ---------------- counts + offsets from top_i, single block ----------------
__global__ __launch_bounds__(256) void k_count(const int* __restrict__ top_i, int* __restrict__ offsets) {
    __shared__ int hist[256][17];
    int tid = threadIdx.x;
    #pragma unroll
    for (int e = 0; e < E_; e++) hist[tid][e] = 0;
    __syncthreads();
    const int* mine = top_i + tid * 32;
    #pragma unroll
    for (int j = 0; j < 32; j++) hist[tid][mine[j]]++;
    __syncthreads();
    if (tid < E_) {
        int s = 0;
        for (int r = 0; r < 256; r++) s += hist[r][tid];
        hist[0][tid] = s;
    }
    __syncthreads();
    if (tid == 0) {
        int s = 0;
        for (int e = 0; e < E_; e++) { offsets[e] = s; s += hist[0][e]; }
        offsets[E_] = s;
    }
}

// ---------------- deterministic slot assignment by rank, one block per expert ----------------
__global__ __launch_bounds__(256) void k_fillscan(
    const int* __restrict__ top_i, const int* __restrict__ offsets,
    int* __restrict__ slot_token, int* __restrict__ slot_pos)
{
    int e = blockIdx.x;
    int tid = threadIdx.x;
    int lane = tid & 63, w = tid >> 6;
    __shared__ int wsum[4];

    int t0 = tid * 16;
    unsigned f0 = 0, f1 = 0;
    int c = 0;
    #pragma unroll
    for (int j = 0; j < 16; j++) {
        int t = t0 + j;
        int a = top_i[t*2], b = top_i[t*2+1];
        if (a == e)      { f0 |= 1u << j; c++; }
        else if (b == e) { f1 |= 1u << j; c++; }
    }
    int incl = c;
    #pragma unroll
    for (int off = 1; off < 64; off <<= 1) {
        int v = __shfl_up(incl, off);
        if (lane >= off) incl += v;
    }
    if (lane == 63) wsum[w] = incl;
    __syncthreads();
    int wbase = 0;
    for (int i = 0; i < w; i++) wbase += wsum[i];
    int pos = offsets[e] + wbase + (incl - c);
    #pragma unroll
    for (int j = 0; j < 16; j++) {
        int t = t0 + j;
        if ((f0 >> j) & 1u)      { slot_token[pos] = t; slot_pos[t*2]   = pos; pos++; }
        else if ((f1 >> j) & 1u) { slot_token[pos] = t; slot_pos[t*2+1] = pos; pos++; }
    }
}

// ======= Phase A: gate/up GEMMs, R7 geometry + counted-vmcnt barriers (no sched_barrier) =======
__global__ __launch_bounds__(256) void k_mlp1(
    const bf16* __restrict__ xb, const bf16* __restrict__ wgu,
    const bf16* __restrict__ wsg, const bf16* __restrict__ wsu,
    const int* __restrict__ slot_token, const int* __restrict__ offsets,
    bf16* __restrict__ hiddenE, bf16* __restrict__ sh_hid)
{
    int bid = (blockIdx.x & 7) * 640 + (blockIdx.x >> 3);   // bijective XCD swizzle, nwg=5120
    bool expert = bid < 4096;
    int nt, mt, base, cnt;
    const bf16 *Bg, *Bu;
    bf16* outp; int nout;
    if (expert) {
        int e = bid >> 8; int r = bid & 255; nt = r & 7; mt = r >> 3;
        base = offsets[e]; cnt = offsets[e+1] - base;
        if (mt * 128 >= cnt) return;
        const bf16* wb = wgu + (size_t)e * (2 * MI_) * H_;
        Bg = wb + (size_t)(nt * 64) * H_;
        Bu = wb + (size_t)(MI_ + nt * 64) * H_;
        outp = hiddenE; nout = MI_;
    } else {
        int r = bid - 4096; nt = r & 31; mt = r >> 5;
        base = 0; cnt = T_;
        Bg = wsg + (size_t)(nt * 64) * H_;
        Bu = wsu + (size_t)(nt * 64) * H_;
        outp = sh_hid; nout = SI_;
    }

    __shared__ __align__(16) bf16 As0[128 * 64], Bs0[128 * 64];
    __shared__ __align__(16) bf16 As1[128 * 64], Bs1[128 * 64];

    int tid = threadIdx.x, w = tid >> 6, l = tid & 63;
    int lrow8 = l >> 3;                       // row within 8-row staging group
    int col_off = ((l & 7) ^ lrow8) * 8;      // inverse-swizzled global chunk

    const bf16* asrc[4];
    const bf16* bsrc[4];
    #pragma unroll
    for (int g = 0; g < 4; g++) {
        int rt = g * 32 + w * 8 + lrow8;      // row within 128-tile
        int s = mt * 128 + rt; if (s >= cnt) s = cnt - 1;
        asrc[g] = (expert ? xb + (size_t)slot_token[base + s] * H_
                          : xb + (size_t)s * H_) + col_off;
        int half = (rt >> 5) & 1;             // 0=gate, 1=up
        int gcol = ((rt >> 6) << 5) | (rt & 31);  // 0..63 within the 64-col pair group
        bsrc[g] = (half ? Bu : Bg) + (size_t)gcol * H_ + col_off;
    }

    int lr = l & 15, kq = l >> 4;
    int wm = w & 1, wn = w >> 1;              // 2x2 wave grid
    f32x4 acc[4][4];
    #pragma unroll
    for (int mi = 0; mi < 4; mi++)
        #pragma unroll
        for (int ni = 0; ni < 4; ni++) acc[mi][ni] = (f32x4){0.f, 0.f, 0.f, 0.f};

    auto STAGE = [&](bf16* Ad, bf16* Bd, int k0) {
        #pragma unroll
        for (int g = 0; g < 4; g++) {
            gload16(asrc[g] + k0, Ad + (g * 32 + w * 8) * 64);
            gload16(bsrc[g] + k0, Bd + (g * 32 + w * 8) * 64);
        }
    };
    auto COMPUTE = [&](const bf16* Ab, const bf16* Bb) {
        #pragma unroll
        for (int ks = 0; ks < 2; ks++) {
            int cl = ((ks * 4 + kq) ^ (lr & 7)) * 8;   // swizzled read chunk
            bf16x8 af[4], bfr[4];
            #pragma unroll
            for (int mi = 0; mi < 4; mi++)
                af[mi] = *reinterpret_cast<const bf16x8*>(&Ab[(wm * 64 + mi * 16 + lr) * 64 + cl]);
            #pragma unroll
            for (int ni = 0; ni < 4; ni++)
                bfr[ni] = *reinterpret_cast<const bf16x8*>(&Bb[(wn * 64 + ni * 16 + lr) * 64 + cl]);
            #pragma unroll
            for (int mi = 0; mi < 4; mi++)
                #pragma unroll
                for (int ni = 0; ni < 4; ni++)
                    acc[mi][ni] = __builtin_amdgcn_mfma_f32_16x16x32_bf16(af[mi], bfr[ni], acc[mi][ni], 0, 0, 0);
        }
    };

    // counted-vmcnt pipeline: 8 gloads/STAGE; SYNC_VM(8) waits only the PREVIOUS stage.
    STAGE(As0, Bs0, 0);
    for (int k0 = 0; k0 < H_; k0 += 128) {
        SYNC_LGKM0;                          // all waves done reading buf1's old tile
        STAGE(As1, Bs1, k0 + 64);
        SYNC_VM(8);                          // tile k0 landed; k0+64 still in flight
        COMPUTE(As0, Bs0);
        SYNC_LGKM0;                          // all waves done reading buf0
        if (k0 + 128 < H_) {
            STAGE(As0, Bs0, k0 + 128);
            SYNC_VM(8);                      // tile k0+64 landed
        } else {
            SYNC_VM(0);
        }
        COMPUTE(As1, Bs1);
    }

    // epilogue: gate=acc[][ni], up=acc[][ni+2] share col
    #pragma unroll
    for (int mi = 0; mi < 4; mi++)
        #pragma unroll
        for (int ni = 0; ni < 2; ni++)
            #pragma unroll
            for (int r = 0; r < 4; r++) {
                int row = mt * 128 + wm * 64 + mi * 16 + kq * 4 + r;
                if (row < cnt) {
                    int col = nt * 64 + wn * 32 + ni * 16 + lr;
                    float g = acc[mi][ni][r], u = acc[mi][ni + 2][r];
                    float hv = u * (g / (1.f + expf(-g)));
                    outp[(size_t)(base + row) * nout + col] = (bf16)hv;
                }
            }
}

// ======= Phase B: down GEMMs, same counted-vmcnt structure =======
__global__ __launch_bounds__(256) void k_mlp2(
    const bf16* __restrict__ hiddenE, const bf16* __restrict__ sh_hid,
    const bf16* __restrict__ wdn, const bf16* __restrict__ wsd,
    const int* __restrict__ offsets, const float* __restrict__ gate_s,
    bf16* __restrict__ eo, float* __restrict__ out)
{
    int bid = (blockIdx.x & 7) * 544 + (blockIdx.x >> 3);   // bijective XCD swizzle, nwg=4352
    bool expert = bid < 4096;
    int nt, mt, base, cnt, KD;
    const bf16 *Ab, *B0;
    if (expert) {
        int e = bid >> 8; int r = bid & 255; nt = r & 7; mt = r >> 3;
        base = offsets[e]; cnt = offsets[e+1] - base;
        if (mt * 128 >= cnt) return;
        KD = MI_;
        Ab = hiddenE;
        B0 = wdn + (size_t)e * H_ * MI_ + (size_t)(nt * 128) * MI_;
    } else {
        int r = bid - 4096; nt = r & 7; mt = r >> 3;
        base = 0; cnt = T_; KD = SI_;
        Ab = sh_hid;
        B0 = wsd + (size_t)(nt * 128) * SI_;
    }

    __shared__ __align__(16) bf16 As0[128 * 64], Bs0[128 * 64];
    __shared__ __align__(16) bf16 As1[128 * 64], Bs1[128 * 64];

    int tid = threadIdx.x, w = tid >> 6, l = tid & 63;
    int lrow8 = l >> 3;
    int col_off = ((l & 7) ^ lrow8) * 8;

    const bf16* asrc[4];
    const bf16* bsrc[4];
    #pragma unroll
    for (int g = 0; g < 4; g++) {
        int rt = g * 32 + w * 8 + lrow8;
        int s = mt * 128 + rt; if (s >= cnt) s = cnt - 1;
        asrc[g] = Ab + (size_t)(base + s) * KD + col_off;
        bsrc[g] = B0 + (size_t)rt * KD + col_off;
    }

    int lr = l & 15, kq = l >> 4;
    int wm = w & 1, wn = w >> 1;
    f32x4 acc[4][4];
    #pragma unroll
    for (int mi = 0; mi < 4; mi++)
        #pragma unroll
        for (int ni = 0; ni < 4; ni++) acc[mi][ni] = (f32x4){0.f, 0.f, 0.f, 0.f};

    auto STAGE = [&](bf16* Ad, bf16* Bd, int k0) {
        #pragma unroll
        for (int g = 0; g < 4; g++) {
            gload16(asrc[g] + k0, Ad + (g * 32 + w * 8) * 64);
            gload16(bsrc[g] + k0, Bd + (g * 32 + w * 8) * 64);
        }
    };
    auto COMPUTE = [&](const bf16* Abuf, const bf16* Bbuf) {
        #pragma unroll
        for (int ks = 0; ks < 2; ks++) {
            int cl = ((ks * 4 + kq) ^ (lr & 7)) * 8;
            bf16x8 af[4], bfr[4];
            #pragma unroll
            for (int mi = 0; mi < 4; mi++)
                af[mi] = *reinterpret_cast<const bf16x8*>(&Abuf[(wm * 64 + mi * 16 + lr) * 64 + cl]);
            #pragma unroll
            for (int ni = 0; ni < 4; ni++)
                bfr[ni] = *reinterpret_cast<const bf16x8*>(&Bbuf[(wn * 64 + ni * 16 + lr) * 64 + cl]);
            #pragma unroll
            for (int mi = 0; mi < 4; mi++)
                #pragma unroll
                for (int ni = 0; ni < 4; ni++)
                    acc[mi][ni] = __builtin_amdgcn_mfma_f32_16x16x32_bf16(af[mi], bfr[ni], acc[mi][ni], 0, 0, 0);
        }
    };

    STAGE(As0, Bs0, 0);
    for (int k0 = 0; k0 < KD; k0 += 128) {
        SYNC_LGKM0;
        STAGE(As1, Bs1, k0 + 64);
        SYNC_VM(8);
        COMPUTE(As0, Bs0);
        SYNC_LGKM0;
        if (k0 + 128 < KD) {
            STAGE(As0, Bs0, k0 + 128);
            SYNC_VM(8);
        } else {
            SYNC_VM(0);
        }
        COMPUTE(As1, Bs1);
    }

    #pragma unroll
    for (int mi = 0; mi < 4; mi++)
        #pragma unroll
        for (int ni = 0; ni < 4; ni++)
            #pragma unroll
            for (int r = 0; r < 4; r++) {
                int row = mt * 128 + wm * 64 + mi * 16 + kq * 4 + r;
                if (row < cnt) {
                    int col = nt * 128 + wn * 64 + ni * 16 + lr;
                    float v = acc[mi][ni][r];
                    if (expert) eo[(size_t)(base + row) * H_ + col] = (bf16)v;
                    else        out[(size_t)row * H_ + col] = gate_s[row] * v;
                }
            }
}

// ---------------- combine: out += w0*eo[s0] + w1*eo[s1] ----------------
__global__ void k_combine(float* __restrict__ out, const bf16* __restrict__ eo,
                          const int* __restrict__ slot_pos, const float* __restrict__ top_w)
{
    int i = blockIdx.x * blockDim.x + threadIdx.x;
    int t = i >> 8;
    int q = (i & 255) * 4;
    int s0 = slot_pos[t*2], s1 = slot_pos[t*2+1];
    float w0 = top_w[t*2], w1 = top_w[t*2+1];
    bf16x4 e0 = *reinterpret_cast<const bf16x4*>(eo + (size_t)s0 * H_ + q);
    bf16x4 e1 = *reinterpret_cast<const bf16x4*>(eo + (size_t)s1 * H_ + q);
    float4* op = reinterpret_cast<float4*>(out) + i;
    float4 so = *op;
    float4 r;
    r.x = so.x + w0 * (float)e0[0] + w1 * (float)e1[0];
    r.y = so.y + w0 * (float)e0[1] + w1 * (float)e1[1];
    r.z = so.z + w0 * (float)e0[2] + w1 * (float)e1[2];
    r.w = so.w + w0 * (float)e0[3] + w1 * (float)e1[3];
    *op = r;
}

extern "C" void kernel_launch(void* const* d_in, const int* in_sizes, int n_in,
                              void* d_out, int out_size, void* d_ws, size_t ws_size,
                              hipStream_t stream) {
    const float* x    = (const float*)d_in[0];
    const float* rw   = (const float*)d_in[1];
    const float* wgu  = (const float*)d_in[2];
    const float* wdn  = (const float*)d_in[3];
    const float* wsg  = (const float*)d_in[4];
    const float* wsu  = (const float*)d_in[5];
    const float* wsd  = (const float*)d_in[6];
    const float* segw = (const float*)d_in[7];
    float* out    = (float*)d_out;
    float* logits = (float*)d_out + (size_t)T_ * H_;

    char* p = (char*)d_ws;
    bf16* xb      = (bf16*)p;  p += (size_t)T_ * H_ * 2;
    bf16* w_guT   = (bf16*)p;  p += (size_t)E_ * H_ * (2*MI_) * 2;
    bf16* w_dnT   = (bf16*)p;  p += (size_t)E_ * MI_ * H_ * 2;
    bf16* w_sgT   = (bf16*)p;  p += (size_t)H_ * SI_ * 2;
    bf16* w_suT   = (bf16*)p;  p += (size_t)H_ * SI_ * 2;
    bf16* w_sdT   = (bf16*)p;  p += (size_t)SI_ * H_ * 2;
    bf16* hiddenE = (bf16*)p;  p += (size_t)TK_ * MI_ * 2;
    bf16* sh_hid  = (bf16*)p;  p += (size_t)T_ * SI_ * 2;
    bf16* eo      = (bf16*)p;  p += (size_t)TK_ * H_ * 2;
    float* gate_s = (float*)p; p += (size_t)T_ * 4;
    int*  top_i   = (int*)p;   p += (size_t)T_ * 2 * 4;
    float* top_w  = (float*)p; p += (size_t)T_ * 2 * 4;
    int*  slot_pos= (int*)p;   p += (size_t)T_ * 2 * 4;
    int*  slot_tok= (int*)p;   p += (size_t)TK_ * 4;
    int*  offsets = (int*)p;   p += 17 * 4;

    // all weight transposes in one launch; router fuses the x->bf16 convert
    k_transpose_all<<<dim3(30720), dim3(32, 8), 0, stream>>>(
        wgu, wdn, wsg, wsu, wsd, w_guT, w_dnT, w_sgT, w_suT, w_sdT);
    k_router<<<dim3(T_/4), 256, 0, stream>>>(x, rw, segw, logits, top_i, top_w, gate_s, xb);
    k_count<<<dim3(1), 256, 0, stream>>>(top_i, offsets);
    k_fillscan<<<dim3(E_), 256, 0, stream>>>(top_i, offsets, slot_tok, slot_pos);

    // phase A: all gate/up GEMMs in one launch
    k_mlp1<<<dim3(4096 + 1024), 256, 0, stream>>>(xb, w_guT, w_sgT, w_suT, slot_tok, offsets, hiddenE, sh_hid);
    // phase B: all down GEMMs in one launch
    k_mlp2<<<dim3(4096 + 256), 256, 0, stream>>>(hiddenE, sh_hid, w_dnT, w_sdT, offsets, gate_s, eo, out);

    // combine expert contributions into d_out
    k_combine<<<dim3(T_*256/256), 256, 0, stream>>>(out, eo, slot_pos, top_w);
}

// Round 13
// 241.729 us; speedup vs baseline: 1.7037x; 1.7037x over previous
//
#include <hip/hip_runtime.h>
#include <hip/hip_bf16.h>
#include <cstdint>

#define T_  4096
#define H_  1024
#define E_  16
#define MI_ 512
#define SI_ 2048
#define TK_ 8192   // T_ * K(=2)

typedef __bf16 bf16;
typedef bf16  bf16x8 __attribute__((ext_vector_type(8)));
typedef bf16  bf16x4 __attribute__((ext_vector_type(4)));
typedef float f32x4  __attribute__((ext_vector_type(4)));

// async global->LDS, 16B per lane. LDS dest = wave-uniform base + lane*16.
__device__ __forceinline__ void gload16(const bf16* g, bf16* lds) {
    __builtin_amdgcn_global_load_lds(
        (const __attribute__((address_space(1))) void*)(uintptr_t)(const void*)g,
        (__attribute__((address_space(3))) void*)(uintptr_t)(void*)lds,
        16, 0, 0);
}

// ======= prep: 5 weight transposes (blocks 0..30719) + router (blocks 30720..31743) =======
__global__ __launch_bounds__(256) void k_prep(
    const float* __restrict__ wgu, const float* __restrict__ wdn,
    const float* __restrict__ wsg, const float* __restrict__ wsu, const float* __restrict__ wsd,
    bf16* __restrict__ ogu, bf16* __restrict__ odn,
    bf16* __restrict__ osg, bf16* __restrict__ osu, bf16* __restrict__ osd,
    const float* __restrict__ x, const float* __restrict__ rw, const float* __restrict__ segw,
    float* __restrict__ logits_out, int* __restrict__ top_i, float* __restrict__ top_w,
    float* __restrict__ gate_scalar, bf16* __restrict__ xb)
{
    int id = blockIdx.x;
    if (id < 30720) {
        // ---- transpose part: fp32 [R][C] -> bf16 [C][R] ----
        __shared__ float tile[32][33];
        int tx = threadIdx.x & 31, ty = threadIdx.x >> 5;   // (32,8)
        const float* src; bf16* dst; int R, C, bx, by;
        if (id < 16384) {              // wgu: 16 x [1024][1024]
            int s = id >> 10, r = id & 1023;
            src = wgu + (size_t)s * 1048576; dst = ogu + (size_t)s * 1048576;
            R = 1024; C = 1024; bx = r & 31; by = r >> 5;
        } else if (id < 24576) {       // wdn: 16 x [512][1024]
            int k = id - 16384; int s = k >> 9, r = k & 511;
            src = wdn + (size_t)s * 524288; dst = odn + (size_t)s * 524288;
            R = 512; C = 1024; bx = r & 31; by = r >> 5;
        } else if (id < 26624) {       // wsg: [1024][2048]
            int r = id - 24576;
            src = wsg; dst = osg; R = 1024; C = 2048; bx = r & 63; by = r >> 6;
        } else if (id < 28672) {       // wsu: [1024][2048]
            int r = id - 26624;
            src = wsu; dst = osu; R = 1024; C = 2048; bx = r & 63; by = r >> 6;
        } else {                       // wsd: [2048][1024]
            int r = id - 28672;
            src = wsd; dst = osd; R = 2048; C = 1024; bx = r & 31; by = r >> 5;
        }
        int c = bx * 32 + tx;
        #pragma unroll
        for (int i = 0; i < 4; i++) {
            int r_ = by * 32 + ty + i * 8;
            tile[ty + i * 8][tx] = src[(size_t)r_ * C + c];
        }
        __syncthreads();
        int rr = by * 32 + tx;
        #pragma unroll
        for (int i = 0; i < 4; i++) {
            int cc = bx * 32 + ty + i * 8;
            dst[(size_t)cc * R + rr] = (bf16)tile[tx][ty + i * 8];
        }
        return;
    }
    // ---- router part (+ fused x->bf16 convert) ----
    int rb = id - 30720;
    int wid = threadIdx.x >> 6, lane = threadIdx.x & 63;
    int t = rb * 4 + wid;
    const float* xr = x + (size_t)t * H_;
    bf16* xbr = xb + (size_t)t * H_;
    float acc[E_];
    #pragma unroll
    for (int e = 0; e < E_; e++) acc[e] = 0.f;
    float accg = 0.f;
    for (int j = 0; j < H_ / 64; j++) {
        int h = j * 64 + lane;
        float xv = xr[h];
        xbr[h] = (bf16)xv;
        const float4* wrow = reinterpret_cast<const float4*>(rw + (size_t)h * E_);
        #pragma unroll
        for (int q = 0; q < 4; q++) {
            float4 w4 = wrow[q];
            acc[q*4+0] += xv * w4.x; acc[q*4+1] += xv * w4.y;
            acc[q*4+2] += xv * w4.z; acc[q*4+3] += xv * w4.w;
        }
        accg += xv * segw[h];
    }
    #pragma unroll
    for (int off = 32; off >= 1; off >>= 1) {
        #pragma unroll
        for (int e = 0; e < E_; e++) acc[e] += __shfl_xor(acc[e], off);
        accg += __shfl_xor(accg, off);
    }
    if (lane == 0) {
        float* lo = logits_out + (size_t)t * E_;
        #pragma unroll
        for (int e = 0; e < E_; e++) lo[e] = acc[e];
        int i0 = 0; float l0 = acc[0];
        #pragma unroll
        for (int e = 1; e < E_; e++) if (acc[e] > l0) { l0 = acc[e]; i0 = e; }
        int i1 = -1; float l1 = -1e30f;
        #pragma unroll
        for (int e = 0; e < E_; e++) if (e != i0 && acc[e] > l1) { l1 = acc[e]; i1 = e; }
        float w0 = 1.f / (1.f + expf(l1 - l0));
        top_i[t*2] = i0; top_i[t*2+1] = i1;
        top_w[t*2] = w0; top_w[t*2+1] = 1.f - w0;
        gate_scalar[t] = 1.f / (1.f + expf(-accg));
    }
}

// ======= route: 17 blocks. Each recomputes histogram (no inter-block dep). =======
// Blocks 0..15: deterministic rank-scan slot assignment for expert b.
// Block 16: writes global offsets + compact (e,mt) tile worklist.
__global__ __launch_bounds__(256) void k_route(
    const int* __restrict__ top_i,
    int* __restrict__ offsets, int* __restrict__ tile_list, int* __restrict__ n_tiles,
    int* __restrict__ slot_token, int* __restrict__ slot_pos)
{
    __shared__ int hist[256][17];
    __shared__ int offs[17];
    int tid = threadIdx.x;
    #pragma unroll
    for (int e = 0; e < E_; e++) hist[tid][e] = 0;
    __syncthreads();
    const int* mine = top_i + tid * 32;
    #pragma unroll
    for (int j = 0; j < 32; j++) hist[tid][mine[j]]++;
    __syncthreads();
    if (tid < E_) {
        int s = 0;
        for (int r = 0; r < 256; r++) s += hist[r][tid];
        hist[0][tid] = s;
    }
    __syncthreads();
    if (tid == 0) {
        int s = 0;
        for (int e = 0; e < E_; e++) { offs[e] = s; s += hist[0][e]; }
        offs[E_] = s;
    }
    __syncthreads();

    if (blockIdx.x == 16) {
        if (tid == 0) {
            int n = 0;
            for (int e = 0; e < E_; e++) {
                offsets[e] = offs[e];
                int c = hist[0][e];
                int ntl = (c + 127) >> 7;
                for (int m = 0; m < ntl; m++) tile_list[n++] = (e << 8) | m;
            }
            offsets[E_] = offs[E_];
            n_tiles[0] = n;
        }
        return;
    }

    int e = blockIdx.x;
    int lane = tid & 63, w = tid >> 6;
    __shared__ int wsum[4];
    int t0 = tid * 16;
    unsigned f0 = 0, f1 = 0;
    int c = 0;
    #pragma unroll
    for (int j = 0; j < 16; j++) {
        int t = t0 + j;
        int a = top_i[t*2], b = top_i[t*2+1];
        if (a == e)      { f0 |= 1u << j; c++; }
        else if (b == e) { f1 |= 1u << j; c++; }
    }
    int incl = c;
    #pragma unroll
    for (int off = 1; off < 64; off <<= 1) {
        int v = __shfl_up(incl, off);
        if (lane >= off) incl += v;
    }
    if (lane == 63) wsum[w] = incl;
    __syncthreads();
    int wbase = 0;
    for (int i = 0; i < w; i++) wbase += wsum[i];
    int pos = offs[e] + wbase + (incl - c);
    #pragma unroll
    for (int j = 0; j < 16; j++) {
        int t = t0 + j;
        if ((f0 >> j) & 1u)      { slot_token[pos] = t; slot_pos[t*2]   = pos; pos++; }
        else if ((f1 >> j) & 1u) { slot_token[pos] = t; slot_pos[t*2+1] = pos; pos++; }
    }
}

// ======= Phase A (R7-proven): gate/up GEMMs. Shared blocks first, expert via worklist. =======
// grid 1664 = 1024 shared + 640 expert-worklist. Static dbuf, 2x2 waves, __syncthreads.
__global__ __launch_bounds__(256) void k_mlp1(
    const bf16* __restrict__ xb, const bf16* __restrict__ wgu,
    const bf16* __restrict__ wsg, const bf16* __restrict__ wsu,
    const int* __restrict__ slot_token, const int* __restrict__ offsets,
    const int* __restrict__ tile_list, const int* __restrict__ n_tiles,
    bf16* __restrict__ hiddenE, bf16* __restrict__ sh_hid)
{
    int bid = (blockIdx.x & 7) * 208 + (blockIdx.x >> 3);   // bijective XCD swizzle, nwg=1664
    bool expert = bid >= 1024;
    int nt, mt, base, cnt;
    const bf16 *Bg, *Bu;
    bf16* outp; int nout;
    if (expert) {
        int r = bid - 1024;
        int idx = r >> 3;
        if (idx >= n_tiles[0]) return;
        int te = tile_list[idx];
        int e = te >> 8; mt = te & 255; nt = r & 7;
        base = offsets[e]; cnt = offsets[e+1] - base;
        const bf16* wb = wgu + (size_t)e * (2 * MI_) * H_;
        Bg = wb + (size_t)(nt * 64) * H_;
        Bu = wb + (size_t)(MI_ + nt * 64) * H_;
        outp = hiddenE; nout = MI_;
    } else {
        nt = bid & 31; mt = bid >> 5;
        base = 0; cnt = T_;
        Bg = wsg + (size_t)(nt * 64) * H_;
        Bu = wsu + (size_t)(nt * 64) * H_;
        outp = sh_hid; nout = SI_;
    }

    __shared__ __align__(16) bf16 As0[128 * 64], Bs0[128 * 64];
    __shared__ __align__(16) bf16 As1[128 * 64], Bs1[128 * 64];

    int tid = threadIdx.x, w = tid >> 6, l = tid & 63;
    int lrow8 = l >> 3;                       // row within 8-row staging group
    int col_off = ((l & 7) ^ lrow8) * 8;      // inverse-swizzled global chunk

    const bf16* asrc[4];
    const bf16* bsrc[4];
    #pragma unroll
    for (int g = 0; g < 4; g++) {
        int rt = g * 32 + w * 8 + lrow8;      // row within 128-tile
        int s = mt * 128 + rt; if (s >= cnt) s = cnt - 1;
        asrc[g] = (expert ? xb + (size_t)slot_token[base + s] * H_
                          : xb + (size_t)s * H_) + col_off;
        int half = (rt >> 5) & 1;             // 0=gate, 1=up
        int gcol = ((rt >> 6) << 5) | (rt & 31);
        bsrc[g] = (half ? Bu : Bg) + (size_t)gcol * H_ + col_off;
    }

    int lr = l & 15, kq = l >> 4;
    int wm = w & 1, wn = w >> 1;              // 2x2 wave grid
    f32x4 acc[4][4];
    #pragma unroll
    for (int mi = 0; mi < 4; mi++)
        #pragma unroll
        for (int ni = 0; ni < 4; ni++) acc[mi][ni] = (f32x4){0.f, 0.f, 0.f, 0.f};

    auto STAGE = [&](bf16* Ad, bf16* Bd, int k0) {
        #pragma unroll
        for (int g = 0; g < 4; g++) {
            gload16(asrc[g] + k0, Ad + (g * 32 + w * 8) * 64);
            gload16(bsrc[g] + k0, Bd + (g * 32 + w * 8) * 64);
        }
    };
    auto COMPUTE = [&](const bf16* Ab, const bf16* Bb) {
        #pragma unroll
        for (int ks = 0; ks < 2; ks++) {
            int cl = ((ks * 4 + kq) ^ (lr & 7)) * 8;   // swizzled read chunk
            bf16x8 af[4], bfr[4];
            #pragma unroll
            for (int mi = 0; mi < 4; mi++)
                af[mi] = *reinterpret_cast<const bf16x8*>(&Ab[(wm * 64 + mi * 16 + lr) * 64 + cl]);
            #pragma unroll
            for (int ni = 0; ni < 4; ni++)
                bfr[ni] = *reinterpret_cast<const bf16x8*>(&Bb[(wn * 64 + ni * 16 + lr) * 64 + cl]);
            #pragma unroll
            for (int mi = 0; mi < 4; mi++)
                #pragma unroll
                for (int ni = 0; ni < 4; ni++)
                    acc[mi][ni] = __builtin_amdgcn_mfma_f32_16x16x32_bf16(af[mi], bfr[ni], acc[mi][ni], 0, 0, 0);
        }
    };

    STAGE(As0, Bs0, 0);
    __syncthreads();
    for (int k0 = 0; k0 < H_; k0 += 128) {
        STAGE(As1, Bs1, k0 + 64);     // flies during COMPUTE(As0)
        COMPUTE(As0, Bs0);
        __syncthreads();
        if (k0 + 128 < H_) STAGE(As0, Bs0, k0 + 128);
        COMPUTE(As1, Bs1);
        __syncthreads();
    }

    #pragma unroll
    for (int mi = 0; mi < 4; mi++)
        #pragma unroll
        for (int ni = 0; ni < 2; ni++)
            #pragma unroll
            for (int r = 0; r < 4; r++) {
                int row = mt * 128 + wm * 64 + mi * 16 + kq * 4 + r;
                if (row < cnt) {
                    int col = nt * 64 + wn * 32 + ni * 16 + lr;
                    float g = acc[mi][ni][r], u = acc[mi][ni + 2][r];
                    float hv = u * (g / (1.f + expf(-g)));
                    outp[(size_t)(base + row) * nout + col] = (bf16)hv;
                }
            }
}

// ======= Phase B (R7-proven): down GEMMs. Shared first (K=2048 longest), expert via worklist. =======
// grid 896 = 256 shared + 640 expert-worklist.
__global__ __launch_bounds__(256) void k_mlp2(
    const bf16* __restrict__ hiddenE, const bf16* __restrict__ sh_hid,
    const bf16* __restrict__ wdn, const bf16* __restrict__ wsd,
    const int* __restrict__ offsets, const float* __restrict__ gate_s,
    const int* __restrict__ tile_list, const int* __restrict__ n_tiles,
    bf16* __restrict__ eo, float* __restrict__ out)
{
    int bid = (blockIdx.x & 7) * 112 + (blockIdx.x >> 3);   // bijective XCD swizzle, nwg=896
    bool expert = bid >= 256;
    int nt, mt, base, cnt, KD;
    const bf16 *Ab, *B0;
    if (expert) {
        int r = bid - 256;
        int idx = r >> 3;
        if (idx >= n_tiles[0]) return;
        int te = tile_list[idx];
        int e = te >> 8; mt = te & 255; nt = r & 7;
        base = offsets[e]; cnt = offsets[e+1] - base;
        KD = MI_;
        Ab = hiddenE;
        B0 = wdn + (size_t)e * H_ * MI_ + (size_t)(nt * 128) * MI_;
    } else {
        nt = bid & 7; mt = bid >> 3;
        base = 0; cnt = T_; KD = SI_;
        Ab = sh_hid;
        B0 = wsd + (size_t)(nt * 128) * SI_;
    }

    __shared__ __align__(16) bf16 As0[128 * 64], Bs0[128 * 64];
    __shared__ __align__(16) bf16 As1[128 * 64], Bs1[128 * 64];

    int tid = threadIdx.x, w = tid >> 6, l = tid & 63;
    int lrow8 = l >> 3;
    int col_off = ((l & 7) ^ lrow8) * 8;

    const bf16* asrc[4];
    const bf16* bsrc[4];
    #pragma unroll
    for (int g = 0; g < 4; g++) {
        int rt = g * 32 + w * 8 + lrow8;
        int s = mt * 128 + rt; if (s >= cnt) s = cnt - 1;
        asrc[g] = Ab + (size_t)(base + s) * KD + col_off;
        bsrc[g] = B0 + (size_t)rt * KD + col_off;
    }

    int lr = l & 15, kq = l >> 4;
    int wm = w & 1, wn = w >> 1;
    f32x4 acc[4][4];
    #pragma unroll
    for (int mi = 0; mi < 4; mi++)
        #pragma unroll
        for (int ni = 0; ni < 4; ni++) acc[mi][ni] = (f32x4){0.f, 0.f, 0.f, 0.f};

    auto STAGE = [&](bf16* Ad, bf16* Bd, int k0) {
        #pragma unroll
        for (int g = 0; g < 4; g++) {
            gload16(asrc[g] + k0, Ad + (g * 32 + w * 8) * 64);
            gload16(bsrc[g] + k0, Bd + (g * 32 + w * 8) * 64);
        }
    };
    auto COMPUTE = [&](const bf16* Abuf, const bf16* Bbuf) {
        #pragma unroll
        for (int ks = 0; ks < 2; ks++) {
            int cl = ((ks * 4 + kq) ^ (lr & 7)) * 8;
            bf16x8 af[4], bfr[4];
            #pragma unroll
            for (int mi = 0; mi < 4; mi++)
                af[mi] = *reinterpret_cast<const bf16x8*>(&Abuf[(wm * 64 + mi * 16 + lr) * 64 + cl]);
            #pragma unroll
            for (int ni = 0; ni < 4; ni++)
                bfr[ni] = *reinterpret_cast<const bf16x8*>(&Bbuf[(wn * 64 + ni * 16 + lr) * 64 + cl]);
            #pragma unroll
            for (int mi = 0; mi < 4; mi++)
                #pragma unroll
                for (int ni = 0; ni < 4; ni++)
                    acc[mi][ni] = __builtin_amdgcn_mfma_f32_16x16x32_bf16(af[mi], bfr[ni], acc[mi][ni], 0, 0, 0);
        }
    };

    STAGE(As0, Bs0, 0);
    __syncthreads();
    for (int k0 = 0; k0 < KD; k0 += 128) {
        STAGE(As1, Bs1, k0 + 64);
        COMPUTE(As0, Bs0);
        __syncthreads();
        if (k0 + 128 < KD) STAGE(As0, Bs0, k0 + 128);
        COMPUTE(As1, Bs1);
        __syncthreads();
    }

    #pragma unroll
    for (int mi = 0; mi < 4; mi++)
        #pragma unroll
        for (int ni = 0; ni < 4; ni++)
            #pragma unroll
            for (int r = 0; r < 4; r++) {
                int row = mt * 128 + wm * 64 + mi * 16 + kq * 4 + r;
                if (row < cnt) {
                    int col = nt * 128 + wn * 64 + ni * 16 + lr;
                    float v = acc[mi][ni][r];
                    if (expert) eo[(size_t)(base + row) * H_ + col] = (bf16)v;
                    else        out[(size_t)row * H_ + col] = gate_s[row] * v;
                }
            }
}

// ---------------- combine: out += w0*eo[s0] + w1*eo[s1] ----------------
__global__ void k_combine(float* __restrict__ out, const bf16* __restrict__ eo,
                          const int* __restrict__ slot_pos, const float* __restrict__ top_w)
{
    int i = blockIdx.x * blockDim.x + threadIdx.x;
    int t = i >> 8;
    int q = (i & 255) * 4;
    int s0 = slot_pos[t*2], s1 = slot_pos[t*2+1];
    float w0 = top_w[t*2], w1 = top_w[t*2+1];
    bf16x4 e0 = *reinterpret_cast<const bf16x4*>(eo + (size_t)s0 * H_ + q);
    bf16x4 e1 = *reinterpret_cast<const bf16x4*>(eo + (size_t)s1 * H_ + q);
    float4* op = reinterpret_cast<float4*>(out) + i;
    float4 so = *op;
    float4 r;
    r.x = so.x + w0 * (float)e0[0] + w1 * (float)e1[0];
    r.y = so.y + w0 * (float)e0[1] + w1 * (float)e1[1];
    r.z = so.z + w0 * (float)e0[2] + w1 * (float)e1[2];
    r.w = so.w + w0 * (float)e0[3] + w1 * (float)e1[3];
    *op = r;
}

extern "C" void kernel_launch(void* const* d_in, const int* in_sizes, int n_in,
                              void* d_out, int out_size, void* d_ws, size_t ws_size,
                              hipStream_t stream) {
    const float* x    = (const float*)d_in[0];
    const float* rw   = (const float*)d_in[1];
    const float* wgu  = (const float*)d_in[2];
    const float* wdn  = (const float*)d_in[3];
    const float* wsg  = (const float*)d_in[4];
    const float* wsu  = (const float*)d_in[5];
    const float* wsd  = (const float*)d_in[6];
    const float* segw = (const float*)d_in[7];
    float* out    = (float*)d_out;
    float* logits = (float*)d_out + (size_t)T_ * H_;

    char* p = (char*)d_ws;
    bf16* xb      = (bf16*)p;  p += (size_t)T_ * H_ * 2;
    bf16* w_guT   = (bf16*)p;  p += (size_t)E_ * H_ * (2*MI_) * 2;
    bf16* w_dnT   = (bf16*)p;  p += (size_t)E_ * MI_ * H_ * 2;
    bf16* w_sgT   = (bf16*)p;  p += (size_t)H_ * SI_ * 2;
    bf16* w_suT   = (bf16*)p;  p += (size_t)H_ * SI_ * 2;
    bf16* w_sdT   = (bf16*)p;  p += (size_t)SI_ * H_ * 2;
    bf16* hiddenE = (bf16*)p;  p += (size_t)TK_ * MI_ * 2;
    bf16* sh_hid  = (bf16*)p;  p += (size_t)T_ * SI_ * 2;
    bf16* eo      = (bf16*)p;  p += (size_t)TK_ * H_ * 2;
    float* gate_s = (float*)p; p += (size_t)T_ * 4;
    int*  top_i   = (int*)p;   p += (size_t)T_ * 2 * 4;
    float* top_w  = (float*)p; p += (size_t)T_ * 2 * 4;
    int*  slot_pos= (int*)p;   p += (size_t)T_ * 2 * 4;
    int*  slot_tok= (int*)p;   p += (size_t)TK_ * 4;
    int*  offsets = (int*)p;   p += 32 * 4;
    int*  tile_list=(int*)p;   p += 128 * 4;
    int*  n_tiles = (int*)p;   p += 4 * 4;

    // 1: transposes + router in one launch
    k_prep<<<dim3(31744), 256, 0, stream>>>(
        wgu, wdn, wsg, wsu, wsd, w_guT, w_dnT, w_sgT, w_suT, w_sdT,
        x, rw, segw, logits, top_i, top_w, gate_s, xb);
    // 2: offsets + worklist + slot assignment (17 independent blocks)
    k_route<<<dim3(17), 256, 0, stream>>>(top_i, offsets, tile_list, n_tiles, slot_tok, slot_pos);
    // 3: all gate/up GEMMs
    k_mlp1<<<dim3(1664), 256, 0, stream>>>(xb, w_guT, w_sgT, w_suT, slot_tok, offsets,
                                           tile_list, n_tiles, hiddenE, sh_hid);
    // 4: all down GEMMs
    k_mlp2<<<dim3(896), 256, 0, stream>>>(hiddenE, sh_hid, w_dnT, w_sdT, offsets, gate_s,
                                          tile_list, n_tiles, eo, out);
    // 5: combine expert contributions
    k_combine<<<dim3(T_*256/256), 256, 0, stream>>>(out, eo, slot_pos, top_w);
}

// Round 14
// 218.599 us; speedup vs baseline: 1.8840x; 1.1058x over previous
//
#include <hip/hip_runtime.h>
#include <hip/hip_bf16.h>
#include <cstdint>

#define T_  4096
#define H_  1024
#define E_  16
#define MI_ 512
#define SI_ 2048
#define TK_ 8192   // T_ * K(=2)

typedef __bf16 bf16;
typedef bf16  bf16x8 __attribute__((ext_vector_type(8)));
typedef bf16  bf16x4 __attribute__((ext_vector_type(4)));
typedef float f32x4  __attribute__((ext_vector_type(4)));

// async global->LDS, 16B per lane. LDS dest = wave-uniform base + lane*16.
__device__ __forceinline__ void gload16(const bf16* g, bf16* lds) {
    __builtin_amdgcn_global_load_lds(
        (const __attribute__((address_space(1))) void*)(uintptr_t)(const void*)g,
        (__attribute__((address_space(3))) void*)(uintptr_t)(void*)lds,
        16, 0, 0);
}

// ======= prep: 5 weight transposes (blocks 0..30719) + router (blocks 30720..31743) =======
__global__ __launch_bounds__(256) void k_prep(
    const float* __restrict__ wgu, const float* __restrict__ wdn,
    const float* __restrict__ wsg, const float* __restrict__ wsu, const float* __restrict__ wsd,
    bf16* __restrict__ ogu, bf16* __restrict__ odn,
    bf16* __restrict__ osg, bf16* __restrict__ osu, bf16* __restrict__ osd,
    const float* __restrict__ x, const float* __restrict__ rw, const float* __restrict__ segw,
    float* __restrict__ logits_out, int* __restrict__ top_i, float* __restrict__ top_w,
    float* __restrict__ gate_scalar, bf16* __restrict__ xb)
{
    int id = blockIdx.x;
    if (id < 30720) {
        // ---- transpose part: fp32 [R][C] -> bf16 [C][R] ----
        __shared__ float tile[32][33];
        int tx = threadIdx.x & 31, ty = threadIdx.x >> 5;   // (32,8)
        const float* src; bf16* dst; int R, C, bx, by;
        if (id < 16384) {              // wgu: 16 x [1024][1024]
            int s = id >> 10, r = id & 1023;
            src = wgu + (size_t)s * 1048576; dst = ogu + (size_t)s * 1048576;
            R = 1024; C = 1024; bx = r & 31; by = r >> 5;
        } else if (id < 24576) {       // wdn: 16 x [512][1024]
            int k = id - 16384; int s = k >> 9, r = k & 511;
            src = wdn + (size_t)s * 524288; dst = odn + (size_t)s * 524288;
            R = 512; C = 1024; bx = r & 31; by = r >> 5;
        } else if (id < 26624) {       // wsg: [1024][2048]
            int r = id - 24576;
            src = wsg; dst = osg; R = 1024; C = 2048; bx = r & 63; by = r >> 6;
        } else if (id < 28672) {       // wsu: [1024][2048]
            int r = id - 26624;
            src = wsu; dst = osu; R = 1024; C = 2048; bx = r & 63; by = r >> 6;
        } else {                       // wsd: [2048][1024]
            int r = id - 28672;
            src = wsd; dst = osd; R = 2048; C = 1024; bx = r & 31; by = r >> 5;
        }
        int c = bx * 32 + tx;
        #pragma unroll
        for (int i = 0; i < 4; i++) {
            int r_ = by * 32 + ty + i * 8;
            tile[ty + i * 8][tx] = src[(size_t)r_ * C + c];
        }
        __syncthreads();
        int rr = by * 32 + tx;
        #pragma unroll
        for (int i = 0; i < 4; i++) {
            int cc = bx * 32 + ty + i * 8;
            dst[(size_t)cc * R + rr] = (bf16)tile[tx][ty + i * 8];
        }
        return;
    }
    // ---- router part (+ fused x->bf16 convert) ----
    int rb = id - 30720;
    int wid = threadIdx.x >> 6, lane = threadIdx.x & 63;
    int t = rb * 4 + wid;
    const float* xr = x + (size_t)t * H_;
    bf16* xbr = xb + (size_t)t * H_;
    float acc[E_];
    #pragma unroll
    for (int e = 0; e < E_; e++) acc[e] = 0.f;
    float accg = 0.f;
    for (int j = 0; j < H_ / 64; j++) {
        int h = j * 64 + lane;
        float xv = xr[h];
        xbr[h] = (bf16)xv;
        const float4* wrow = reinterpret_cast<const float4*>(rw + (size_t)h * E_);
        #pragma unroll
        for (int q = 0; q < 4; q++) {
            float4 w4 = wrow[q];
            acc[q*4+0] += xv * w4.x; acc[q*4+1] += xv * w4.y;
            acc[q*4+2] += xv * w4.z; acc[q*4+3] += xv * w4.w;
        }
        accg += xv * segw[h];
    }
    #pragma unroll
    for (int off = 32; off >= 1; off >>= 1) {
        #pragma unroll
        for (int e = 0; e < E_; e++) acc[e] += __shfl_xor(acc[e], off);
        accg += __shfl_xor(accg, off);
    }
    if (lane == 0) {
        float* lo = logits_out + (size_t)t * E_;
        #pragma unroll
        for (int e = 0; e < E_; e++) lo[e] = acc[e];
        int i0 = 0; float l0 = acc[0];
        #pragma unroll
        for (int e = 1; e < E_; e++) if (acc[e] > l0) { l0 = acc[e]; i0 = e; }
        int i1 = -1; float l1 = -1e30f;
        #pragma unroll
        for (int e = 0; e < E_; e++) if (e != i0 && acc[e] > l1) { l1 = acc[e]; i1 = e; }
        float w0 = 1.f / (1.f + expf(l1 - l0));
        top_i[t*2] = i0; top_i[t*2+1] = i1;
        top_w[t*2] = w0; top_w[t*2+1] = 1.f - w0;
        gate_scalar[t] = 1.f / (1.f + expf(-accg));
    }
}

// ======= route: 17 blocks, each recomputes histogram (no inter-block dep). =======
// Blocks 0..15: deterministic rank-scan slot assignment for expert b. Block 16: offsets.
__global__ __launch_bounds__(256) void k_route(
    const int* __restrict__ top_i, int* __restrict__ offsets,
    int* __restrict__ slot_token, int* __restrict__ slot_pos)
{
    __shared__ int hist[256][17];
    __shared__ int offs[17];
    int tid = threadIdx.x;
    #pragma unroll
    for (int e = 0; e < E_; e++) hist[tid][e] = 0;
    __syncthreads();
    const int* mine = top_i + tid * 32;
    #pragma unroll
    for (int j = 0; j < 32; j++) hist[tid][mine[j]]++;
    __syncthreads();
    if (tid < E_) {
        int s = 0;
        for (int r = 0; r < 256; r++) s += hist[r][tid];
        hist[0][tid] = s;
    }
    __syncthreads();
    if (tid == 0) {
        int s = 0;
        for (int e = 0; e < E_; e++) { offs[e] = s; s += hist[0][e]; }
        offs[E_] = s;
    }
    __syncthreads();

    if (blockIdx.x == 16) {
        if (tid <= E_) offsets[tid] = offs[tid];
        return;
    }

    int e = blockIdx.x;
    int lane = tid & 63, w = tid >> 6;
    __shared__ int wsum[4];
    int t0 = tid * 16;
    unsigned f0 = 0, f1 = 0;
    int c = 0;
    #pragma unroll
    for (int j = 0; j < 16; j++) {
        int t = t0 + j;
        int a = top_i[t*2], b = top_i[t*2+1];
        if (a == e)      { f0 |= 1u << j; c++; }
        else if (b == e) { f1 |= 1u << j; c++; }
    }
    int incl = c;
    #pragma unroll
    for (int off = 1; off < 64; off <<= 1) {
        int v = __shfl_up(incl, off);
        if (lane >= off) incl += v;
    }
    if (lane == 63) wsum[w] = incl;
    __syncthreads();
    int wbase = 0;
    for (int i = 0; i < w; i++) wbase += wsum[i];
    int pos = offs[e] + wbase + (incl - c);
    #pragma unroll
    for (int j = 0; j < 16; j++) {
        int t = t0 + j;
        if ((f0 >> j) & 1u)      { slot_token[pos] = t; slot_pos[t*2]   = pos; pos++; }
        else if ((f1 >> j) & 1u) { slot_token[pos] = t; slot_pos[t*2+1] = pos; pos++; }
    }
}

// ======= Phase A (208-us config, exact): expert gate/up (bid<4096) + shared gate/up, K=1024, BK=64 =======
// Static double-buffer, 2x2 wave grid (wave=64x64), __syncthreads-managed barriers.
__global__ __launch_bounds__(256) void k_mlp1(
    const bf16* __restrict__ xb, const bf16* __restrict__ wgu,
    const bf16* __restrict__ wsg, const bf16* __restrict__ wsu,
    const int* __restrict__ slot_token, const int* __restrict__ offsets,
    bf16* __restrict__ hiddenE, bf16* __restrict__ sh_hid)
{
    int bid = blockIdx.x;
    bool expert = bid < 4096;
    int nt, mt, base, cnt;
    const bf16 *Bg, *Bu;
    bf16* outp; int nout;
    if (expert) {
        int e = bid >> 8; int r = bid & 255; nt = r & 7; mt = r >> 3;
        base = offsets[e]; cnt = offsets[e+1] - base;
        if (mt * 128 >= cnt) return;
        const bf16* wb = wgu + (size_t)e * (2 * MI_) * H_;
        Bg = wb + (size_t)(nt * 64) * H_;
        Bu = wb + (size_t)(MI_ + nt * 64) * H_;
        outp = hiddenE; nout = MI_;
    } else {
        int r = bid - 4096; nt = r & 31; mt = r >> 5;
        base = 0; cnt = T_;
        Bg = wsg + (size_t)(nt * 64) * H_;
        Bu = wsu + (size_t)(nt * 64) * H_;
        outp = sh_hid; nout = SI_;
    }

    __shared__ __align__(16) bf16 As0[128 * 64], Bs0[128 * 64];
    __shared__ __align__(16) bf16 As1[128 * 64], Bs1[128 * 64];

    int tid = threadIdx.x, w = tid >> 6, l = tid & 63;
    int lrow8 = l >> 3;                       // row within 8-row staging group
    int col_off = ((l & 7) ^ lrow8) * 8;      // inverse-swizzled global chunk

    const bf16* asrc[4];
    const bf16* bsrc[4];
    #pragma unroll
    for (int g = 0; g < 4; g++) {
        int rt = g * 32 + w * 8 + lrow8;      // row within 128-tile
        int s = mt * 128 + rt; if (s >= cnt) s = cnt - 1;
        asrc[g] = (expert ? xb + (size_t)slot_token[base + s] * H_
                          : xb + (size_t)s * H_) + col_off;
        int half = (rt >> 5) & 1;             // 0=gate, 1=up
        int gcol = ((rt >> 6) << 5) | (rt & 31);  // 0..63 within the 64-col pair group
        bsrc[g] = (half ? Bu : Bg) + (size_t)gcol * H_ + col_off;
    }

    int lr = l & 15, kq = l >> 4;
    int wm = w & 1, wn = w >> 1;              // 2x2 wave grid
    f32x4 acc[4][4];
    #pragma unroll
    for (int mi = 0; mi < 4; mi++)
        #pragma unroll
        for (int ni = 0; ni < 4; ni++) acc[mi][ni] = (f32x4){0.f, 0.f, 0.f, 0.f};

    auto STAGE = [&](bf16* Ad, bf16* Bd, int k0) {
        #pragma unroll
        for (int g = 0; g < 4; g++) {
            gload16(asrc[g] + k0, Ad + (g * 32 + w * 8) * 64);
            gload16(bsrc[g] + k0, Bd + (g * 32 + w * 8) * 64);
        }
    };
    auto COMPUTE = [&](const bf16* Ab, const bf16* Bb) {
        #pragma unroll
        for (int ks = 0; ks < 2; ks++) {
            int cl = ((ks * 4 + kq) ^ (lr & 7)) * 8;   // swizzled read chunk
            bf16x8 af[4], bfr[4];
            #pragma unroll
            for (int mi = 0; mi < 4; mi++)
                af[mi] = *reinterpret_cast<const bf16x8*>(&Ab[(wm * 64 + mi * 16 + lr) * 64 + cl]);
            #pragma unroll
            for (int ni = 0; ni < 4; ni++)
                bfr[ni] = *reinterpret_cast<const bf16x8*>(&Bb[(wn * 64 + ni * 16 + lr) * 64 + cl]);
            #pragma unroll
            for (int mi = 0; mi < 4; mi++)
                #pragma unroll
                for (int ni = 0; ni < 4; ni++)
                    acc[mi][ni] = __builtin_amdgcn_mfma_f32_16x16x32_bf16(af[mi], bfr[ni], acc[mi][ni], 0, 0, 0);
        }
    };

    STAGE(As0, Bs0, 0);
    __syncthreads();
    for (int k0 = 0; k0 < H_; k0 += 128) {
        STAGE(As1, Bs1, k0 + 64);     // flies during COMPUTE(As0)
        COMPUTE(As0, Bs0);
        __syncthreads();
        if (k0 + 128 < H_) STAGE(As0, Bs0, k0 + 128);  // flies during COMPUTE(As1)
        COMPUTE(As1, Bs1);
        __syncthreads();
    }

    // epilogue: gate=acc[][ni], up=acc[][ni+2] share col
    #pragma unroll
    for (int mi = 0; mi < 4; mi++)
        #pragma unroll
        for (int ni = 0; ni < 2; ni++)
            #pragma unroll
            for (int r = 0; r < 4; r++) {
                int row = mt * 128 + wm * 64 + mi * 16 + kq * 4 + r;
                if (row < cnt) {
                    int col = nt * 64 + wn * 32 + ni * 16 + lr;
                    float g = acc[mi][ni][r], u = acc[mi][ni + 2][r];
                    float hv = u * (g / (1.f + expf(-g)));
                    outp[(size_t)(base + row) * nout + col] = (bf16)hv;
                }
            }
}

// ======= Phase B (208-us config, exact): expert down (K=512) + shared down (K=2048), BK=64 =======
__global__ __launch_bounds__(256) void k_mlp2(
    const bf16* __restrict__ hiddenE, const bf16* __restrict__ sh_hid,
    const bf16* __restrict__ wdn, const bf16* __restrict__ wsd,
    const int* __restrict__ offsets, const float* __restrict__ gate_s,
    bf16* __restrict__ eo, float* __restrict__ out)
{
    int bid = blockIdx.x;
    bool expert = bid < 4096;
    int nt, mt, base, cnt, KD;
    const bf16 *Ab, *B0;
    if (expert) {
        int e = bid >> 8; int r = bid & 255; nt = r & 7; mt = r >> 3;
        base = offsets[e]; cnt = offsets[e+1] - base;
        if (mt * 128 >= cnt) return;
        KD = MI_;
        Ab = hiddenE;
        B0 = wdn + (size_t)e * H_ * MI_ + (size_t)(nt * 128) * MI_;
    } else {
        int r = bid - 4096; nt = r & 7; mt = r >> 3;
        base = 0; cnt = T_; KD = SI_;
        Ab = sh_hid;
        B0 = wsd + (size_t)(nt * 128) * SI_;
    }

    __shared__ __align__(16) bf16 As0[128 * 64], Bs0[128 * 64];
    __shared__ __align__(16) bf16 As1[128 * 64], Bs1[128 * 64];

    int tid = threadIdx.x, w = tid >> 6, l = tid & 63;
    int lrow8 = l >> 3;
    int col_off = ((l & 7) ^ lrow8) * 8;

    const bf16* asrc[4];
    const bf16* bsrc[4];
    #pragma unroll
    for (int g = 0; g < 4; g++) {
        int rt = g * 32 + w * 8 + lrow8;
        int s = mt * 128 + rt; if (s >= cnt) s = cnt - 1;
        asrc[g] = Ab + (size_t)(base + s) * KD + col_off;
        bsrc[g] = B0 + (size_t)rt * KD + col_off;
    }

    int lr = l & 15, kq = l >> 4;
    int wm = w & 1, wn = w >> 1;
    f32x4 acc[4][4];
    #pragma unroll
    for (int mi = 0; mi < 4; mi++)
        #pragma unroll
        for (int ni = 0; ni < 4; ni++) acc[mi][ni] = (f32x4){0.f, 0.f, 0.f, 0.f};

    auto STAGE = [&](bf16* Ad, bf16* Bd, int k0) {
        #pragma unroll
        for (int g = 0; g < 4; g++) {
            gload16(asrc[g] + k0, Ad + (g * 32 + w * 8) * 64);
            gload16(bsrc[g] + k0, Bd + (g * 32 + w * 8) * 64);
        }
    };
    auto COMPUTE = [&](const bf16* Abuf, const bf16* Bbuf) {
        #pragma unroll
        for (int ks = 0; ks < 2; ks++) {
            int cl = ((ks * 4 + kq) ^ (lr & 7)) * 8;
            bf16x8 af[4], bfr[4];
            #pragma unroll
            for (int mi = 0; mi < 4; mi++)
                af[mi] = *reinterpret_cast<const bf16x8*>(&Abuf[(wm * 64 + mi * 16 + lr) * 64 + cl]);
            #pragma unroll
            for (int ni = 0; ni < 4; ni++)
                bfr[ni] = *reinterpret_cast<const bf16x8*>(&Bbuf[(wn * 64 + ni * 16 + lr) * 64 + cl]);
            #pragma unroll
            for (int mi = 0; mi < 4; mi++)
                #pragma unroll
                for (int ni = 0; ni < 4; ni++)
                    acc[mi][ni] = __builtin_amdgcn_mfma_f32_16x16x32_bf16(af[mi], bfr[ni], acc[mi][ni], 0, 0, 0);
        }
    };

    STAGE(As0, Bs0, 0);
    __syncthreads();
    for (int k0 = 0; k0 < KD; k0 += 128) {
        STAGE(As1, Bs1, k0 + 64);
        COMPUTE(As0, Bs0);
        __syncthreads();
        if (k0 + 128 < KD) STAGE(As0, Bs0, k0 + 128);
        COMPUTE(As1, Bs1);
        __syncthreads();
    }

    #pragma unroll
    for (int mi = 0; mi < 4; mi++)
        #pragma unroll
        for (int ni = 0; ni < 4; ni++)
            #pragma unroll
            for (int r = 0; r < 4; r++) {
                int row = mt * 128 + wm * 64 + mi * 16 + kq * 4 + r;
                if (row < cnt) {
                    int col = nt * 128 + wn * 64 + ni * 16 + lr;
                    float v = acc[mi][ni][r];
                    if (expert) eo[(size_t)(base + row) * H_ + col] = (bf16)v;
                    else        out[(size_t)row * H_ + col] = gate_s[row] * v;
                }
            }
}

// ---------------- combine: out += w0*eo[s0] + w1*eo[s1] ----------------
__global__ void k_combine(float* __restrict__ out, const bf16* __restrict__ eo,
                          const int* __restrict__ slot_pos, const float* __restrict__ top_w)
{
    int i = blockIdx.x * blockDim.x + threadIdx.x;
    int t = i >> 8;
    int q = (i & 255) * 4;
    int s0 = slot_pos[t*2], s1 = slot_pos[t*2+1];
    float w0 = top_w[t*2], w1 = top_w[t*2+1];
    bf16x4 e0 = *reinterpret_cast<const bf16x4*>(eo + (size_t)s0 * H_ + q);
    bf16x4 e1 = *reinterpret_cast<const bf16x4*>(eo + (size_t)s1 * H_ + q);
    float4* op = reinterpret_cast<float4*>(out) + i;
    float4 so = *op;
    float4 r;
    r.x = so.x + w0 * (float)e0[0] + w1 * (float)e1[0];
    r.y = so.y + w0 * (float)e0[1] + w1 * (float)e1[1];
    r.z = so.z + w0 * (float)e0[2] + w1 * (float)e1[2];
    r.w = so.w + w0 * (float)e0[3] + w1 * (float)e1[3];
    *op = r;
}

extern "C" void kernel_launch(void* const* d_in, const int* in_sizes, int n_in,
                              void* d_out, int out_size, void* d_ws, size_t ws_size,
                              hipStream_t stream) {
    const float* x    = (const float*)d_in[0];
    const float* rw   = (const float*)d_in[1];
    const float* wgu  = (const float*)d_in[2];
    const float* wdn  = (const float*)d_in[3];
    const float* wsg  = (const float*)d_in[4];
    const float* wsu  = (const float*)d_in[5];
    const float* wsd  = (const float*)d_in[6];
    const float* segw = (const float*)d_in[7];
    float* out    = (float*)d_out;
    float* logits = (float*)d_out + (size_t)T_ * H_;

    char* p = (char*)d_ws;
    bf16* xb      = (bf16*)p;  p += (size_t)T_ * H_ * 2;
    bf16* w_guT   = (bf16*)p;  p += (size_t)E_ * H_ * (2*MI_) * 2;
    bf16* w_dnT   = (bf16*)p;  p += (size_t)E_ * MI_ * H_ * 2;
    bf16* w_sgT   = (bf16*)p;  p += (size_t)H_ * SI_ * 2;
    bf16* w_suT   = (bf16*)p;  p += (size_t)H_ * SI_ * 2;
    bf16* w_sdT   = (bf16*)p;  p += (size_t)SI_ * H_ * 2;
    bf16* hiddenE = (bf16*)p;  p += (size_t)TK_ * MI_ * 2;
    bf16* sh_hid  = (bf16*)p;  p += (size_t)T_ * SI_ * 2;
    bf16* eo      = (bf16*)p;  p += (size_t)TK_ * H_ * 2;
    float* gate_s = (float*)p; p += (size_t)T_ * 4;
    int*  top_i   = (int*)p;   p += (size_t)T_ * 2 * 4;
    float* top_w  = (float*)p; p += (size_t)T_ * 2 * 4;
    int*  slot_pos= (int*)p;   p += (size_t)T_ * 2 * 4;
    int*  slot_tok= (int*)p;   p += (size_t)TK_ * 4;
    int*  offsets = (int*)p;   p += 32 * 4;

    // 1: transposes + router in one launch
    k_prep<<<dim3(31744), 256, 0, stream>>>(
        wgu, wdn, wsg, wsu, wsd, w_guT, w_dnT, w_sgT, w_suT, w_sdT,
        x, rw, segw, logits, top_i, top_w, gate_s, xb);
    // 2: offsets + slot assignment (17 independent blocks)
    k_route<<<dim3(17), 256, 0, stream>>>(top_i, offsets, slot_tok, slot_pos);
    // 3: all gate/up GEMMs (208-us config grids, early-returns included)
    k_mlp1<<<dim3(4096 + 1024), 256, 0, stream>>>(xb, w_guT, w_sgT, w_suT, slot_tok, offsets, hiddenE, sh_hid);
    // 4: all down GEMMs
    k_mlp2<<<dim3(4096 + 256), 256, 0, stream>>>(hiddenE, sh_hid, w_dnT, w_sdT, offsets, gate_s, eo, out);
    // 5: combine expert contributions
    k_combine<<<dim3(T_*256/256), 256, 0, stream>>>(out, eo, slot_pos, top_w);
}

// Round 15
// 208.945 us; speedup vs baseline: 1.9710x; 1.0462x over previous
//
#include <hip/hip_runtime.h>
#include <hip/hip_bf16.h>
#include <cstdint>

#define T_  4096
#define H_  1024
#define E_  16
#define MI_ 512
#define SI_ 2048
#define TK_ 8192   // T_ * K(=2)

typedef __bf16 bf16;
typedef bf16  bf16x8 __attribute__((ext_vector_type(8)));
typedef bf16  bf16x4 __attribute__((ext_vector_type(4)));
typedef float f32x4  __attribute__((ext_vector_type(4)));

// async global->LDS, 16B per lane. LDS dest = wave-uniform base + lane*16.
__device__ __forceinline__ void gload16(const bf16* g, bf16* lds) {
    __builtin_amdgcn_global_load_lds(
        (const __attribute__((address_space(1))) void*)(uintptr_t)(const void*)g,
        (__attribute__((address_space(3))) void*)(uintptr_t)(void*)lds,
        16, 0, 0);
}

// ---------------- all 5 weight transposes, one launch: fp32 [R][C] -> bf16 [C][R] ----------------
__global__ void k_transpose_all(
    const float* __restrict__ wgu, const float* __restrict__ wdn,
    const float* __restrict__ wsg, const float* __restrict__ wsu, const float* __restrict__ wsd,
    bf16* __restrict__ ogu, bf16* __restrict__ odn,
    bf16* __restrict__ osg, bf16* __restrict__ osu, bf16* __restrict__ osd)
{
    __shared__ float tile[32][33];
    int id = blockIdx.x;
    const float* src; bf16* dst; int R, C, bx, by;
    if (id < 16384) {              // wgu: 16 x [1024][1024]
        int s = id >> 10, r = id & 1023;
        src = wgu + (size_t)s * 1048576; dst = ogu + (size_t)s * 1048576;
        R = 1024; C = 1024; bx = r & 31; by = r >> 5;
    } else if (id < 24576) {       // wdn: 16 x [512][1024]
        int k = id - 16384; int s = k >> 9, r = k & 511;
        src = wdn + (size_t)s * 524288; dst = odn + (size_t)s * 524288;
        R = 512; C = 1024; bx = r & 31; by = r >> 5;
    } else if (id < 26624) {       // wsg: [1024][2048]
        int r = id - 24576;
        src = wsg; dst = osg; R = 1024; C = 2048; bx = r & 63; by = r >> 6;
    } else if (id < 28672) {       // wsu: [1024][2048]
        int r = id - 26624;
        src = wsu; dst = osu; R = 1024; C = 2048; bx = r & 63; by = r >> 6;
    } else {                       // wsd: [2048][1024]
        int r = id - 28672;
        src = wsd; dst = osd; R = 2048; C = 1024; bx = r & 31; by = r >> 5;
    }
    int c = bx * 32 + threadIdx.x;
    #pragma unroll
    for (int i = 0; i < 4; i++) {
        int r_ = by * 32 + threadIdx.y + i * 8;
        tile[threadIdx.y + i * 8][threadIdx.x] = src[(size_t)r_ * C + c];
    }
    __syncthreads();
    int rr = by * 32 + threadIdx.x;
    #pragma unroll
    for (int i = 0; i < 4; i++) {
        int cc = bx * 32 + threadIdx.y + i * 8;
        dst[(size_t)cc * R + rr] = (bf16)tile[threadIdx.x][threadIdx.y + i * 8];
    }
}

// ---------------- router + x->bf16 convert fused. NO atomics. ----------------
__global__ __launch_bounds__(256) void k_router(
    const float* __restrict__ x, const float* __restrict__ rw,
    const float* __restrict__ segw, float* __restrict__ logits_out,
    int* __restrict__ top_i, float* __restrict__ top_w,
    float* __restrict__ gate_scalar, bf16* __restrict__ xb)
{
    int wid = threadIdx.x >> 6, lane = threadIdx.x & 63;
    int t = blockIdx.x * 4 + wid;
    const float* xr = x + (size_t)t * H_;
    bf16* xbr = xb + (size_t)t * H_;
    float acc[E_];
    #pragma unroll
    for (int e = 0; e < E_; e++) acc[e] = 0.f;
    float accg = 0.f;
    for (int j = 0; j < H_ / 64; j++) {
        int h = j * 64 + lane;
        float xv = xr[h];
        xbr[h] = (bf16)xv;                    // fused convert
        const float4* wrow = reinterpret_cast<const float4*>(rw + (size_t)h * E_);
        #pragma unroll
        for (int q = 0; q < 4; q++) {
            float4 w4 = wrow[q];
            acc[q*4+0] += xv * w4.x; acc[q*4+1] += xv * w4.y;
            acc[q*4+2] += xv * w4.z; acc[q*4+3] += xv * w4.w;
        }
        accg += xv * segw[h];
    }
    #pragma unroll
    for (int off = 32; off >= 1; off >>= 1) {
        #pragma unroll
        for (int e = 0; e < E_; e++) acc[e] += __shfl_xor(acc[e], off);
        accg += __shfl_xor(accg, off);
    }
    if (lane == 0) {
        float* lo = logits_out + (size_t)t * E_;
        #pragma unroll
        for (int e = 0; e < E_; e++) lo[e] = acc[e];
        int i0 = 0; float l0 = acc[0];
        #pragma unroll
        for (int e = 1; e < E_; e++) if (acc[e] > l0) { l0 = acc[e]; i0 = e; }
        int i1 = -1; float l1 = -1e30f;
        #pragma unroll
        for (int e = 0; e < E_; e++) if (e != i0 && acc[e] > l1) { l1 = acc[e]; i1 = e; }
        float w0 = 1.f / (1.f + expf(l1 - l0));
        top_i[t*2] = i0; top_i[t*2+1] = i1;
        top_w[t*2] = w0; top_w[t*2+1] = 1.f - w0;
        gate_scalar[t] = 1.f / (1.f + expf(-accg));
    }
}

// ---------------- counts + offsets from top_i, single block ----------------
__global__ __launch_bounds__(256) void k_count(const int* __restrict__ top_i, int* __restrict__ offsets) {
    __shared__ int hist[256][17];
    int tid = threadIdx.x;
    #pragma unroll
    for (int e = 0; e < E_; e++) hist[tid][e] = 0;
    __syncthreads();
    const int* mine = top_i + tid * 32;
    #pragma unroll
    for (int j = 0; j < 32; j++) hist[tid][mine[j]]++;
    __syncthreads();
    if (tid < E_) {
        int s = 0;
        for (int r = 0; r < 256; r++) s += hist[r][tid];
        hist[0][tid] = s;
    }
    __syncthreads();
    if (tid == 0) {
        int s = 0;
        for (int e = 0; e < E_; e++) { offsets[e] = s; s += hist[0][e]; }
        offsets[E_] = s;
    }
}

// ---------------- deterministic slot assignment by rank, one block per expert ----------------
__global__ __launch_bounds__(256) void k_fillscan(
    const int* __restrict__ top_i, const int* __restrict__ offsets,
    int* __restrict__ slot_token, int* __restrict__ slot_pos)
{
    int e = blockIdx.x;
    int tid = threadIdx.x;
    int lane = tid & 63, w = tid >> 6;
    __shared__ int wsum[4];

    int t0 = tid * 16;
    unsigned f0 = 0, f1 = 0;
    int c = 0;
    #pragma unroll
    for (int j = 0; j < 16; j++) {
        int t = t0 + j;
        int a = top_i[t*2], b = top_i[t*2+1];
        if (a == e)      { f0 |= 1u << j; c++; }
        else if (b == e) { f1 |= 1u << j; c++; }
    }
    int incl = c;
    #pragma unroll
    for (int off = 1; off < 64; off <<= 1) {
        int v = __shfl_up(incl, off);
        if (lane >= off) incl += v;
    }
    if (lane == 63) wsum[w] = incl;
    __syncthreads();
    int wbase = 0;
    for (int i = 0; i < w; i++) wbase += wsum[i];
    int pos = offsets[e] + wbase + (incl - c);
    #pragma unroll
    for (int j = 0; j < 16; j++) {
        int t = t0 + j;
        if ((f0 >> j) & 1u)      { slot_token[pos] = t; slot_pos[t*2]   = pos; pos++; }
        else if ((f1 >> j) & 1u) { slot_token[pos] = t; slot_pos[t*2+1] = pos; pos++; }
    }
}

// ======= Phase A (R7-proven): expert gate/up (bid<4096) + shared gate/up, K=1024, BK=64 =======
// Static double-buffer, 2x2 wave grid (wave=64x64), __syncthreads-managed barriers.
// Bs interleaves gate/up in 32-row groups so each wave owns matching gate+up cols.
__global__ __launch_bounds__(256) void k_mlp1(
    const bf16* __restrict__ xb, const bf16* __restrict__ wgu,
    const bf16* __restrict__ wsg, const bf16* __restrict__ wsu,
    const int* __restrict__ slot_token, const int* __restrict__ offsets,
    bf16* __restrict__ hiddenE, bf16* __restrict__ sh_hid)
{
    int bid = blockIdx.x;
    bool expert = bid < 4096;
    int nt, mt, base, cnt;
    const bf16 *Bg, *Bu;
    bf16* outp; int nout;
    if (expert) {
        int e = bid >> 8; int r = bid & 255; nt = r & 7; mt = r >> 3;
        base = offsets[e]; cnt = offsets[e+1] - base;
        if (mt * 128 >= cnt) return;
        const bf16* wb = wgu + (size_t)e * (2 * MI_) * H_;
        Bg = wb + (size_t)(nt * 64) * H_;
        Bu = wb + (size_t)(MI_ + nt * 64) * H_;
        outp = hiddenE; nout = MI_;
    } else {
        int r = bid - 4096; nt = r & 31; mt = r >> 5;
        base = 0; cnt = T_;
        Bg = wsg + (size_t)(nt * 64) * H_;
        Bu = wsu + (size_t)(nt * 64) * H_;
        outp = sh_hid; nout = SI_;
    }

    __shared__ __align__(16) bf16 As0[128 * 64], Bs0[128 * 64];
    __shared__ __align__(16) bf16 As1[128 * 64], Bs1[128 * 64];

    int tid = threadIdx.x, w = tid >> 6, l = tid & 63;
    int lrow8 = l >> 3;                       // row within 8-row staging group
    int col_off = ((l & 7) ^ lrow8) * 8;      // inverse-swizzled global chunk

    const bf16* asrc[4];
    const bf16* bsrc[4];
    #pragma unroll
    for (int g = 0; g < 4; g++) {
        int rt = g * 32 + w * 8 + lrow8;      // row within 128-tile
        int s = mt * 128 + rt; if (s >= cnt) s = cnt - 1;
        asrc[g] = (expert ? xb + (size_t)slot_token[base + s] * H_
                          : xb + (size_t)s * H_) + col_off;
        int half = (rt >> 5) & 1;             // 0=gate, 1=up
        int gcol = ((rt >> 6) << 5) | (rt & 31);  // 0..63 within the 64-col pair group
        bsrc[g] = (half ? Bu : Bg) + (size_t)gcol * H_ + col_off;
    }

    int lr = l & 15, kq = l >> 4;
    int wm = w & 1, wn = w >> 1;              // 2x2 wave grid
    f32x4 acc[4][4];
    #pragma unroll
    for (int mi = 0; mi < 4; mi++)
        #pragma unroll
        for (int ni = 0; ni < 4; ni++) acc[mi][ni] = (f32x4){0.f, 0.f, 0.f, 0.f};

    auto STAGE = [&](bf16* Ad, bf16* Bd, int k0) {
        #pragma unroll
        for (int g = 0; g < 4; g++) {
            gload16(asrc[g] + k0, Ad + (g * 32 + w * 8) * 64);
            gload16(bsrc[g] + k0, Bd + (g * 32 + w * 8) * 64);
        }
    };
    auto COMPUTE = [&](const bf16* Ab, const bf16* Bb) {
        #pragma unroll
        for (int ks = 0; ks < 2; ks++) {
            int cl = ((ks * 4 + kq) ^ (lr & 7)) * 8;   // swizzled read chunk
            bf16x8 af[4], bfr[4];
            #pragma unroll
            for (int mi = 0; mi < 4; mi++)
                af[mi] = *reinterpret_cast<const bf16x8*>(&Ab[(wm * 64 + mi * 16 + lr) * 64 + cl]);
            #pragma unroll
            for (int ni = 0; ni < 4; ni++)
                bfr[ni] = *reinterpret_cast<const bf16x8*>(&Bb[(wn * 64 + ni * 16 + lr) * 64 + cl]);
            #pragma unroll
            for (int mi = 0; mi < 4; mi++)
                #pragma unroll
                for (int ni = 0; ni < 4; ni++)
                    acc[mi][ni] = __builtin_amdgcn_mfma_f32_16x16x32_bf16(af[mi], bfr[ni], acc[mi][ni], 0, 0, 0);
        }
    };

    STAGE(As0, Bs0, 0);
    __syncthreads();
    for (int k0 = 0; k0 < H_; k0 += 128) {
        STAGE(As1, Bs1, k0 + 64);     // flies during COMPUTE(As0)
        COMPUTE(As0, Bs0);
        __syncthreads();
        if (k0 + 128 < H_) STAGE(As0, Bs0, k0 + 128);  // flies during COMPUTE(As1)
        COMPUTE(As1, Bs1);
        __syncthreads();
    }

    // epilogue: gate=acc[][ni], up=acc[][ni+2] share col
    #pragma unroll
    for (int mi = 0; mi < 4; mi++)
        #pragma unroll
        for (int ni = 0; ni < 2; ni++)
            #pragma unroll
            for (int r = 0; r < 4; r++) {
                int row = mt * 128 + wm * 64 + mi * 16 + kq * 4 + r;
                if (row < cnt) {
                    int col = nt * 64 + wn * 32 + ni * 16 + lr;
                    float g = acc[mi][ni][r], u = acc[mi][ni + 2][r];
                    float hv = u * (g / (1.f + expf(-g)));
                    outp[(size_t)(base + row) * nout + col] = (bf16)hv;
                }
            }
}

// ======= Phase B (R7-proven): expert down (K=512) + shared down (K=2048), BK=64 =======
__global__ __launch_bounds__(256) void k_mlp2(
    const bf16* __restrict__ hiddenE, const bf16* __restrict__ sh_hid,
    const bf16* __restrict__ wdn, const bf16* __restrict__ wsd,
    const int* __restrict__ offsets, const float* __restrict__ gate_s,
    bf16* __restrict__ eo, float* __restrict__ out)
{
    int bid = blockIdx.x;
    bool expert = bid < 4096;
    int nt, mt, base, cnt, KD;
    const bf16 *Ab, *B0;
    if (expert) {
        int e = bid >> 8; int r = bid & 255; nt = r & 7; mt = r >> 3;
        base = offsets[e]; cnt = offsets[e+1] - base;
        if (mt * 128 >= cnt) return;
        KD = MI_;
        Ab = hiddenE;
        B0 = wdn + (size_t)e * H_ * MI_ + (size_t)(nt * 128) * MI_;
    } else {
        int r = bid - 4096; nt = r & 7; mt = r >> 3;
        base = 0; cnt = T_; KD = SI_;
        Ab = sh_hid;
        B0 = wsd + (size_t)(nt * 128) * SI_;
    }

    __shared__ __align__(16) bf16 As0[128 * 64], Bs0[128 * 64];
    __shared__ __align__(16) bf16 As1[128 * 64], Bs1[128 * 64];

    int tid = threadIdx.x, w = tid >> 6, l = tid & 63;
    int lrow8 = l >> 3;
    int col_off = ((l & 7) ^ lrow8) * 8;

    const bf16* asrc[4];
    const bf16* bsrc[4];
    #pragma unroll
    for (int g = 0; g < 4; g++) {
        int rt = g * 32 + w * 8 + lrow8;
        int s = mt * 128 + rt; if (s >= cnt) s = cnt - 1;
        asrc[g] = Ab + (size_t)(base + s) * KD + col_off;
        bsrc[g] = B0 + (size_t)rt * KD + col_off;
    }

    int lr = l & 15, kq = l >> 4;
    int wm = w & 1, wn = w >> 1;
    f32x4 acc[4][4];
    #pragma unroll
    for (int mi = 0; mi < 4; mi++)
        #pragma unroll
        for (int ni = 0; ni < 4; ni++) acc[mi][ni] = (f32x4){0.f, 0.f, 0.f, 0.f};

    auto STAGE = [&](bf16* Ad, bf16* Bd, int k0) {
        #pragma unroll
        for (int g = 0; g < 4; g++) {
            gload16(asrc[g] + k0, Ad + (g * 32 + w * 8) * 64);
            gload16(bsrc[g] + k0, Bd + (g * 32 + w * 8) * 64);
        }
    };
    auto COMPUTE = [&](const bf16* Abuf, const bf16* Bbuf) {
        #pragma unroll
        for (int ks = 0; ks < 2; ks++) {
            int cl = ((ks * 4 + kq) ^ (lr & 7)) * 8;
            bf16x8 af[4], bfr[4];
            #pragma unroll
            for (int mi = 0; mi < 4; mi++)
                af[mi] = *reinterpret_cast<const bf16x8*>(&Abuf[(wm * 64 + mi * 16 + lr) * 64 + cl]);
            #pragma unroll
            for (int ni = 0; ni < 4; ni++)
                bfr[ni] = *reinterpret_cast<const bf16x8*>(&Bbuf[(wn * 64 + ni * 16 + lr) * 64 + cl]);
            #pragma unroll
            for (int mi = 0; mi < 4; mi++)
                #pragma unroll
                for (int ni = 0; ni < 4; ni++)
                    acc[mi][ni] = __builtin_amdgcn_mfma_f32_16x16x32_bf16(af[mi], bfr[ni], acc[mi][ni], 0, 0, 0);
        }
    };

    STAGE(As0, Bs0, 0);
    __syncthreads();
    for (int k0 = 0; k0 < KD; k0 += 128) {
        STAGE(As1, Bs1, k0 + 64);
        COMPUTE(As0, Bs0);
        __syncthreads();
        if (k0 + 128 < KD) STAGE(As0, Bs0, k0 + 128);
        COMPUTE(As1, Bs1);
        __syncthreads();
    }

    #pragma unroll
    for (int mi = 0; mi < 4; mi++)
        #pragma unroll
        for (int ni = 0; ni < 4; ni++)
            #pragma unroll
            for (int r = 0; r < 4; r++) {
                int row = mt * 128 + wm * 64 + mi * 16 + kq * 4 + r;
                if (row < cnt) {
                    int col = nt * 128 + wn * 64 + ni * 16 + lr;
                    float v = acc[mi][ni][r];
                    if (expert) eo[(size_t)(base + row) * H_ + col] = (bf16)v;
                    else        out[(size_t)row * H_ + col] = gate_s[row] * v;
                }
            }
}

// ---------------- combine: out += w0*eo[s0] + w1*eo[s1] ----------------
__global__ void k_combine(float* __restrict__ out, const bf16* __restrict__ eo,
                          const int* __restrict__ slot_pos, const float* __restrict__ top_w)
{
    int i = blockIdx.x * blockDim.x + threadIdx.x;
    int t = i >> 8;
    int q = (i & 255) * 4;
    int s0 = slot_pos[t*2], s1 = slot_pos[t*2+1];
    float w0 = top_w[t*2], w1 = top_w[t*2+1];
    bf16x4 e0 = *reinterpret_cast<const bf16x4*>(eo + (size_t)s0 * H_ + q);
    bf16x4 e1 = *reinterpret_cast<const bf16x4*>(eo + (size_t)s1 * H_ + q);
    float4* op = reinterpret_cast<float4*>(out) + i;
    float4 so = *op;
    float4 r;
    r.x = so.x + w0 * (float)e0[0] + w1 * (float)e1[0];
    r.y = so.y + w0 * (float)e0[1] + w1 * (float)e1[1];
    r.z = so.z + w0 * (float)e0[2] + w1 * (float)e1[2];
    r.w = so.w + w0 * (float)e0[3] + w1 * (float)e1[3];
    *op = r;
}

extern "C" void kernel_launch(void* const* d_in, const int* in_sizes, int n_in,
                              void* d_out, int out_size, void* d_ws, size_t ws_size,
                              hipStream_t stream) {
    const float* x    = (const float*)d_in[0];
    const float* rw   = (const float*)d_in[1];
    const float* wgu  = (const float*)d_in[2];
    const float* wdn  = (const float*)d_in[3];
    const float* wsg  = (const float*)d_in[4];
    const float* wsu  = (const float*)d_in[5];
    const float* wsd  = (const float*)d_in[6];
    const float* segw = (const float*)d_in[7];
    float* out    = (float*)d_out;
    float* logits = (float*)d_out + (size_t)T_ * H_;

    char* p = (char*)d_ws;
    bf16* xb      = (bf16*)p;  p += (size_t)T_ * H_ * 2;
    bf16* w_guT   = (bf16*)p;  p += (size_t)E_ * H_ * (2*MI_) * 2;
    bf16* w_dnT   = (bf16*)p;  p += (size_t)E_ * MI_ * H_ * 2;
    bf16* w_sgT   = (bf16*)p;  p += (size_t)H_ * SI_ * 2;
    bf16* w_suT   = (bf16*)p;  p += (size_t)H_ * SI_ * 2;
    bf16* w_sdT   = (bf16*)p;  p += (size_t)SI_ * H_ * 2;
    bf16* hiddenE = (bf16*)p;  p += (size_t)TK_ * MI_ * 2;
    bf16* sh_hid  = (bf16*)p;  p += (size_t)T_ * SI_ * 2;
    bf16* eo      = (bf16*)p;  p += (size_t)TK_ * H_ * 2;
    float* gate_s = (float*)p; p += (size_t)T_ * 4;
    int*  top_i   = (int*)p;   p += (size_t)T_ * 2 * 4;
    float* top_w  = (float*)p; p += (size_t)T_ * 2 * 4;
    int*  slot_pos= (int*)p;   p += (size_t)T_ * 2 * 4;
    int*  slot_tok= (int*)p;   p += (size_t)TK_ * 4;
    int*  offsets = (int*)p;   p += 17 * 4;

    // all weight transposes in one launch; router fuses the x->bf16 convert
    k_transpose_all<<<dim3(30720), dim3(32, 8), 0, stream>>>(
        wgu, wdn, wsg, wsu, wsd, w_guT, w_dnT, w_sgT, w_suT, w_sdT);
    k_router<<<dim3(T_/4), 256, 0, stream>>>(x, rw, segw, logits, top_i, top_w, gate_s, xb);
    k_count<<<dim3(1), 256, 0, stream>>>(top_i, offsets);
    k_fillscan<<<dim3(E_), 256, 0, stream>>>(top_i, offsets, slot_tok, slot_pos);

    // phase A: all gate/up GEMMs in one launch (R7-proven kernel)
    k_mlp1<<<dim3(4096 + 1024), 256, 0, stream>>>(xb, w_guT, w_sgT, w_suT, slot_tok, offsets, hiddenE, sh_hid);
    // phase B: all down GEMMs in one launch (R7-proven kernel)
    k_mlp2<<<dim3(4096 + 256), 256, 0, stream>>>(hiddenE, sh_hid, w_dnT, w_sdT, offsets, gate_s, eo, out);

    // combine expert contributions into d_out
    k_combine<<<dim3(T_*256/256), 256, 0, stream>>>(out, eo, slot_pos, top_w);
}

// Round 16
// 195.683 us; speedup vs baseline: 2.1046x; 1.0678x over previous
//
#include <hip/hip_runtime.h>
#include <hip/hip_bf16.h>
#include <cstdint>

#define T_  4096
#define H_  1024
#define E_  16
#define MI_ 512
#define SI_ 2048
#define TK_ 8192   // T_ * K(=2)

typedef __bf16 bf16;
typedef bf16  bf16x8 __attribute__((ext_vector_type(8)));
typedef bf16  bf16x4 __attribute__((ext_vector_type(4)));
typedef float f32x4  __attribute__((ext_vector_type(4)));

// async global->LDS, 16B per lane. LDS dest = wave-uniform base + lane*16.
__device__ __forceinline__ void gload16(const bf16* g, bf16* lds) {
    __builtin_amdgcn_global_load_lds(
        (const __attribute__((address_space(1))) void*)(uintptr_t)(const void*)g,
        (__attribute__((address_space(3))) void*)(uintptr_t)(void*)lds,
        16, 0, 0);
}

// ---------------- all 5 weight transposes, one launch: fp32 [R][C] -> bf16 [C][R] ----------------
__global__ void k_transpose_all(
    const float* __restrict__ wgu, const float* __restrict__ wdn,
    const float* __restrict__ wsg, const float* __restrict__ wsu, const float* __restrict__ wsd,
    bf16* __restrict__ ogu, bf16* __restrict__ odn,
    bf16* __restrict__ osg, bf16* __restrict__ osu, bf16* __restrict__ osd)
{
    __shared__ float tile[32][33];
    int id = blockIdx.x;
    const float* src; bf16* dst; int R, C, bx, by;
    if (id < 16384) {              // wgu: 16 x [1024][1024]
        int s = id >> 10, r = id & 1023;
        src = wgu + (size_t)s * 1048576; dst = ogu + (size_t)s * 1048576;
        R = 1024; C = 1024; bx = r & 31; by = r >> 5;
    } else if (id < 24576) {       // wdn: 16 x [512][1024]
        int k = id - 16384; int s = k >> 9, r = k & 511;
        src = wdn + (size_t)s * 524288; dst = odn + (size_t)s * 524288;
        R = 512; C = 1024; bx = r & 31; by = r >> 5;
    } else if (id < 26624) {       // wsg: [1024][2048]
        int r = id - 24576;
        src = wsg; dst = osg; R = 1024; C = 2048; bx = r & 63; by = r >> 6;
    } else if (id < 28672) {       // wsu: [1024][2048]
        int r = id - 26624;
        src = wsu; dst = osu; R = 1024; C = 2048; bx = r & 63; by = r >> 6;
    } else {                       // wsd: [2048][1024]
        int r = id - 28672;
        src = wsd; dst = osd; R = 2048; C = 1024; bx = r & 31; by = r >> 5;
    }
    int c = bx * 32 + threadIdx.x;
    #pragma unroll
    for (int i = 0; i < 4; i++) {
        int r_ = by * 32 + threadIdx.y + i * 8;
        tile[threadIdx.y + i * 8][threadIdx.x] = src[(size_t)r_ * C + c];
    }
    __syncthreads();
    int rr = by * 32 + threadIdx.x;
    #pragma unroll
    for (int i = 0; i < 4; i++) {
        int cc = bx * 32 + threadIdx.y + i * 8;
        dst[(size_t)cc * R + rr] = (bf16)tile[threadIdx.x][threadIdx.y + i * 8];
    }
}

// ---------------- router + x->bf16 convert fused. NO atomics. ----------------
__global__ __launch_bounds__(256) void k_router(
    const float* __restrict__ x, const float* __restrict__ rw,
    const float* __restrict__ segw, float* __restrict__ logits_out,
    int* __restrict__ top_i, float* __restrict__ top_w,
    float* __restrict__ gate_scalar, bf16* __restrict__ xb)
{
    int wid = threadIdx.x >> 6, lane = threadIdx.x & 63;
    int t = blockIdx.x * 4 + wid;
    const float* xr = x + (size_t)t * H_;
    bf16* xbr = xb + (size_t)t * H_;
    float acc[E_];
    #pragma unroll
    for (int e = 0; e < E_; e++) acc[e] = 0.f;
    float accg = 0.f;
    for (int j = 0; j < H_ / 64; j++) {
        int h = j * 64 + lane;
        float xv = xr[h];
        xbr[h] = (bf16)xv;                    // fused convert
        const float4* wrow = reinterpret_cast<const float4*>(rw + (size_t)h * E_);
        #pragma unroll
        for (int q = 0; q < 4; q++) {
            float4 w4 = wrow[q];
            acc[q*4+0] += xv * w4.x; acc[q*4+1] += xv * w4.y;
            acc[q*4+2] += xv * w4.z; acc[q*4+3] += xv * w4.w;
        }
        accg += xv * segw[h];
    }
    #pragma unroll
    for (int off = 32; off >= 1; off >>= 1) {
        #pragma unroll
        for (int e = 0; e < E_; e++) acc[e] += __shfl_xor(acc[e], off);
        accg += __shfl_xor(accg, off);
    }
    if (lane == 0) {
        float* lo = logits_out + (size_t)t * E_;
        #pragma unroll
        for (int e = 0; e < E_; e++) lo[e] = acc[e];
        int i0 = 0; float l0 = acc[0];
        #pragma unroll
        for (int e = 1; e < E_; e++) if (acc[e] > l0) { l0 = acc[e]; i0 = e; }
        int i1 = -1; float l1 = -1e30f;
        #pragma unroll
        for (int e = 0; e < E_; e++) if (e != i0 && acc[e] > l1) { l1 = acc[e]; i1 = e; }
        float w0 = 1.f / (1.f + expf(l1 - l0));
        top_i[t*2] = i0; top_i[t*2+1] = i1;
        top_w[t*2] = w0; top_w[t*2+1] = 1.f - w0;
        gate_scalar[t] = 1.f / (1.f + expf(-accg));
    }
}

// ---------------- counts + offsets from top_i, single block ----------------
__global__ __launch_bounds__(256) void k_count(const int* __restrict__ top_i, int* __restrict__ offsets) {
    __shared__ int hist[256][17];
    int tid = threadIdx.x;
    #pragma unroll
    for (int e = 0; e < E_; e++) hist[tid][e] = 0;
    __syncthreads();
    const int* mine = top_i + tid * 32;
    #pragma unroll
    for (int j = 0; j < 32; j++) hist[tid][mine[j]]++;
    __syncthreads();
    if (tid < E_) {
        int s = 0;
        for (int r = 0; r < 256; r++) s += hist[r][tid];
        hist[0][tid] = s;
    }
    __syncthreads();
    if (tid == 0) {
        int s = 0;
        for (int e = 0; e < E_; e++) { offsets[e] = s; s += hist[0][e]; }
        offsets[E_] = s;
    }
}

// ---------------- deterministic slot assignment by rank, one block per expert ----------------
__global__ __launch_bounds__(256) void k_fillscan(
    const int* __restrict__ top_i, const int* __restrict__ offsets,
    int* __restrict__ slot_token, int* __restrict__ slot_pos)
{
    int e = blockIdx.x;
    int tid = threadIdx.x;
    int lane = tid & 63, w = tid >> 6;
    __shared__ int wsum[4];

    int t0 = tid * 16;
    unsigned f0 = 0, f1 = 0;
    int c = 0;
    #pragma unroll
    for (int j = 0; j < 16; j++) {
        int t = t0 + j;
        int a = top_i[t*2], b = top_i[t*2+1];
        if (a == e)      { f0 |= 1u << j; c++; }
        else if (b == e) { f1 |= 1u << j; c++; }
    }
    int incl = c;
    #pragma unroll
    for (int off = 1; off < 64; off <<= 1) {
        int v = __shfl_up(incl, off);
        if (lane >= off) incl += v;
    }
    if (lane == 63) wsum[w] = incl;
    __syncthreads();
    int wbase = 0;
    for (int i = 0; i < w; i++) wbase += wsum[i];
    int pos = offsets[e] + wbase + (incl - c);
    #pragma unroll
    for (int j = 0; j < 16; j++) {
        int t = t0 + j;
        if ((f0 >> j) & 1u)      { slot_token[pos] = t; slot_pos[t*2]   = pos; pos++; }
        else if ((f1 >> j) & 1u) { slot_token[pos] = t; slot_pos[t*2+1] = pos; pos++; }
    }
}

// ======= Phase A: gate/up GEMMs. 512 threads, 128x64-pair tile, BK=64, static dbuf. =======
// 8 waves (2m x 4n), wave = 64 rows x 16 paired cols; 4 waves/SIMD for drain cover.
// Bs interleaves gate/up in 16-row groups: wave wn owns matching gate+up fragments.
__global__ __launch_bounds__(512) void k_mlp1(
    const bf16* __restrict__ xb, const bf16* __restrict__ wgu,
    const bf16* __restrict__ wsg, const bf16* __restrict__ wsu,
    const int* __restrict__ slot_token, const int* __restrict__ offsets,
    bf16* __restrict__ hiddenE, bf16* __restrict__ sh_hid)
{
    int bid = blockIdx.x;
    bool expert = bid < 4096;
    int nt, mt, base, cnt;
    const bf16 *Bg, *Bu;
    bf16* outp; int nout;
    if (expert) {
        int e = bid >> 8; int r = bid & 255; nt = r & 7; mt = r >> 3;
        base = offsets[e]; cnt = offsets[e+1] - base;
        if (mt * 128 >= cnt) return;
        const bf16* wb = wgu + (size_t)e * (2 * MI_) * H_;
        Bg = wb + (size_t)(nt * 64) * H_;
        Bu = wb + (size_t)(MI_ + nt * 64) * H_;
        outp = hiddenE; nout = MI_;
    } else {
        int r = bid - 4096; nt = r & 31; mt = r >> 5;
        base = 0; cnt = T_;
        Bg = wsg + (size_t)(nt * 64) * H_;
        Bu = wsu + (size_t)(nt * 64) * H_;
        outp = sh_hid; nout = SI_;
    }

    __shared__ __align__(16) bf16 As0[128 * 64], Bs0[128 * 64];
    __shared__ __align__(16) bf16 As1[128 * 64], Bs1[128 * 64];

    int tid = threadIdx.x, w = tid >> 6, l = tid & 63;
    int lrow8 = l >> 3;                       // row within 8-row staging group
    int col_off = ((l & 7) ^ lrow8) * 8;      // inverse-swizzled global chunk

    // staging: 8 waves x 2 groups cover 128 rows of A and of B
    const bf16* asrc[2];
    const bf16* bsrc[2];
    #pragma unroll
    for (int g = 0; g < 2; g++) {
        int rt = g * 64 + w * 8 + lrow8;      // row within 128-tile
        int s = mt * 128 + rt; if (s >= cnt) s = cnt - 1;
        asrc[g] = (expert ? xb + (size_t)slot_token[base + s] * H_
                          : xb + (size_t)s * H_) + col_off;
        int half = (rt >> 4) & 1;             // 16-row interleave: 0=gate, 1=up
        int gcol = ((rt >> 5) << 4) | (rt & 15);  // 0..63 within the 64-col pair group
        bsrc[g] = (half ? Bu : Bg) + (size_t)gcol * H_ + col_off;
    }

    int lr = l & 15, kq = l >> 4;
    int wm = w & 1, wn = w >> 1;              // 2m x 4n wave grid
    f32x4 acc[4][2];
    #pragma unroll
    for (int mi = 0; mi < 4; mi++)
        #pragma unroll
        for (int ni = 0; ni < 2; ni++) acc[mi][ni] = (f32x4){0.f, 0.f, 0.f, 0.f};

    auto STAGE = [&](bf16* Ad, bf16* Bd, int k0) {
        #pragma unroll
        for (int g = 0; g < 2; g++) {
            gload16(asrc[g] + k0, Ad + (g * 64 + w * 8) * 64);
            gload16(bsrc[g] + k0, Bd + (g * 64 + w * 8) * 64);
        }
    };
    auto COMPUTE = [&](const bf16* Ab, const bf16* Bb) {
        #pragma unroll
        for (int ks = 0; ks < 2; ks++) {
            int cl = ((ks * 4 + kq) ^ (lr & 7)) * 8;   // swizzled read chunk
            bf16x8 af[4], bfr[2];
            #pragma unroll
            for (int mi = 0; mi < 4; mi++)
                af[mi] = *reinterpret_cast<const bf16x8*>(&Ab[(wm * 64 + mi * 16 + lr) * 64 + cl]);
            #pragma unroll
            for (int ni = 0; ni < 2; ni++)
                bfr[ni] = *reinterpret_cast<const bf16x8*>(&Bb[(wn * 32 + ni * 16 + lr) * 64 + cl]);
            #pragma unroll
            for (int mi = 0; mi < 4; mi++)
                #pragma unroll
                for (int ni = 0; ni < 2; ni++)
                    acc[mi][ni] = __builtin_amdgcn_mfma_f32_16x16x32_bf16(af[mi], bfr[ni], acc[mi][ni], 0, 0, 0);
        }
    };

    STAGE(As0, Bs0, 0);
    __syncthreads();
    for (int k0 = 0; k0 < H_; k0 += 128) {
        STAGE(As1, Bs1, k0 + 64);     // flies during COMPUTE(As0)
        COMPUTE(As0, Bs0);
        __syncthreads();
        if (k0 + 128 < H_) STAGE(As0, Bs0, k0 + 128);  // flies during COMPUTE(As1)
        COMPUTE(As1, Bs1);
        __syncthreads();
    }

    // epilogue: gate=acc[mi][0], up=acc[mi][1]; col = nt*64 + wn*16 + lr
    #pragma unroll
    for (int mi = 0; mi < 4; mi++)
        #pragma unroll
        for (int r = 0; r < 4; r++) {
            int row = mt * 128 + wm * 64 + mi * 16 + kq * 4 + r;
            if (row < cnt) {
                int col = nt * 64 + wn * 16 + lr;
                float g = acc[mi][0][r], u = acc[mi][1][r];
                float hv = u * (g / (1.f + expf(-g)));
                outp[(size_t)(base + row) * nout + col] = (bf16)hv;
            }
        }
}

// ======= Phase B: down GEMMs. 512 threads, 128x128 tile, BK=64, static dbuf. =======
__global__ __launch_bounds__(512) void k_mlp2(
    const bf16* __restrict__ hiddenE, const bf16* __restrict__ sh_hid,
    const bf16* __restrict__ wdn, const bf16* __restrict__ wsd,
    const int* __restrict__ offsets, const float* __restrict__ gate_s,
    bf16* __restrict__ eo, float* __restrict__ out)
{
    int bid = blockIdx.x;
    bool expert = bid < 4096;
    int nt, mt, base, cnt, KD;
    const bf16 *Ab, *B0;
    if (expert) {
        int e = bid >> 8; int r = bid & 255; nt = r & 7; mt = r >> 3;
        base = offsets[e]; cnt = offsets[e+1] - base;
        if (mt * 128 >= cnt) return;
        KD = MI_;
        Ab = hiddenE;
        B0 = wdn + (size_t)e * H_ * MI_ + (size_t)(nt * 128) * MI_;
    } else {
        int r = bid - 4096; nt = r & 7; mt = r >> 3;
        base = 0; cnt = T_; KD = SI_;
        Ab = sh_hid;
        B0 = wsd + (size_t)(nt * 128) * SI_;
    }

    __shared__ __align__(16) bf16 As0[128 * 64], Bs0[128 * 64];
    __shared__ __align__(16) bf16 As1[128 * 64], Bs1[128 * 64];

    int tid = threadIdx.x, w = tid >> 6, l = tid & 63;
    int lrow8 = l >> 3;
    int col_off = ((l & 7) ^ lrow8) * 8;

    const bf16* asrc[2];
    const bf16* bsrc[2];
    #pragma unroll
    for (int g = 0; g < 2; g++) {
        int rt = g * 64 + w * 8 + lrow8;
        int s = mt * 128 + rt; if (s >= cnt) s = cnt - 1;
        asrc[g] = Ab + (size_t)(base + s) * KD + col_off;
        bsrc[g] = B0 + (size_t)rt * KD + col_off;
    }

    int lr = l & 15, kq = l >> 4;
    int wm = w & 1, wn = w >> 1;              // 2m x 4n wave grid
    f32x4 acc[4][2];
    #pragma unroll
    for (int mi = 0; mi < 4; mi++)
        #pragma unroll
        for (int ni = 0; ni < 2; ni++) acc[mi][ni] = (f32x4){0.f, 0.f, 0.f, 0.f};

    auto STAGE = [&](bf16* Ad, bf16* Bd, int k0) {
        #pragma unroll
        for (int g = 0; g < 2; g++) {
            gload16(asrc[g] + k0, Ad + (g * 64 + w * 8) * 64);
            gload16(bsrc[g] + k0, Bd + (g * 64 + w * 8) * 64);
        }
    };
    auto COMPUTE = [&](const bf16* Abuf, const bf16* Bbuf) {
        #pragma unroll
        for (int ks = 0; ks < 2; ks++) {
            int cl = ((ks * 4 + kq) ^ (lr & 7)) * 8;
            bf16x8 af[4], bfr[2];
            #pragma unroll
            for (int mi = 0; mi < 4; mi++)
                af[mi] = *reinterpret_cast<const bf16x8*>(&Abuf[(wm * 64 + mi * 16 + lr) * 64 + cl]);
            #pragma unroll
            for (int ni = 0; ni < 2; ni++)
                bfr[ni] = *reinterpret_cast<const bf16x8*>(&Bbuf[(wn * 32 + ni * 16 + lr) * 64 + cl]);
            #pragma unroll
            for (int mi = 0; mi < 4; mi++)
                #pragma unroll
                for (int ni = 0; ni < 2; ni++)
                    acc[mi][ni] = __builtin_amdgcn_mfma_f32_16x16x32_bf16(af[mi], bfr[ni], acc[mi][ni], 0, 0, 0);
        }
    };

    STAGE(As0, Bs0, 0);
    __syncthreads();
    for (int k0 = 0; k0 < KD; k0 += 128) {
        STAGE(As1, Bs1, k0 + 64);
        COMPUTE(As0, Bs0);
        __syncthreads();
        if (k0 + 128 < KD) STAGE(As0, Bs0, k0 + 128);
        COMPUTE(As1, Bs1);
        __syncthreads();
    }

    #pragma unroll
    for (int mi = 0; mi < 4; mi++)
        #pragma unroll
        for (int ni = 0; ni < 2; ni++)
            #pragma unroll
            for (int r = 0; r < 4; r++) {
                int row = mt * 128 + wm * 64 + mi * 16 + kq * 4 + r;
                if (row < cnt) {
                    int col = nt * 128 + wn * 32 + ni * 16 + lr;
                    float v = acc[mi][ni][r];
                    if (expert) eo[(size_t)(base + row) * H_ + col] = (bf16)v;
                    else        out[(size_t)row * H_ + col] = gate_s[row] * v;
                }
            }
}

// ---------------- combine: out += w0*eo[s0] + w1*eo[s1] ----------------
__global__ void k_combine(float* __restrict__ out, const bf16* __restrict__ eo,
                          const int* __restrict__ slot_pos, const float* __restrict__ top_w)
{
    int i = blockIdx.x * blockDim.x + threadIdx.x;
    int t = i >> 8;
    int q = (i & 255) * 4;
    int s0 = slot_pos[t*2], s1 = slot_pos[t*2+1];
    float w0 = top_w[t*2], w1 = top_w[t*2+1];
    bf16x4 e0 = *reinterpret_cast<const bf16x4*>(eo + (size_t)s0 * H_ + q);
    bf16x4 e1 = *reinterpret_cast<const bf16x4*>(eo + (size_t)s1 * H_ + q);
    float4* op = reinterpret_cast<float4*>(out) + i;
    float4 so = *op;
    float4 r;
    r.x = so.x + w0 * (float)e0[0] + w1 * (float)e1[0];
    r.y = so.y + w0 * (float)e0[1] + w1 * (float)e1[1];
    r.z = so.z + w0 * (float)e0[2] + w1 * (float)e1[2];
    r.w = so.w + w0 * (float)e0[3] + w1 * (float)e1[3];
    *op = r;
}

extern "C" void kernel_launch(void* const* d_in, const int* in_sizes, int n_in,
                              void* d_out, int out_size, void* d_ws, size_t ws_size,
                              hipStream_t stream) {
    const float* x    = (const float*)d_in[0];
    const float* rw   = (const float*)d_in[1];
    const float* wgu  = (const float*)d_in[2];
    const float* wdn  = (const float*)d_in[3];
    const float* wsg  = (const float*)d_in[4];
    const float* wsu  = (const float*)d_in[5];
    const float* wsd  = (const float*)d_in[6];
    const float* segw = (const float*)d_in[7];
    float* out    = (float*)d_out;
    float* logits = (float*)d_out + (size_t)T_ * H_;

    char* p = (char*)d_ws;
    bf16* xb      = (bf16*)p;  p += (size_t)T_ * H_ * 2;
    bf16* w_guT   = (bf16*)p;  p += (size_t)E_ * H_ * (2*MI_) * 2;
    bf16* w_dnT   = (bf16*)p;  p += (size_t)E_ * MI_ * H_ * 2;
    bf16* w_sgT   = (bf16*)p;  p += (size_t)H_ * SI_ * 2;
    bf16* w_suT   = (bf16*)p;  p += (size_t)H_ * SI_ * 2;
    bf16* w_sdT   = (bf16*)p;  p += (size_t)SI_ * H_ * 2;
    bf16* hiddenE = (bf16*)p;  p += (size_t)TK_ * MI_ * 2;
    bf16* sh_hid  = (bf16*)p;  p += (size_t)T_ * SI_ * 2;
    bf16* eo      = (bf16*)p;  p += (size_t)TK_ * H_ * 2;
    float* gate_s = (float*)p; p += (size_t)T_ * 4;
    int*  top_i   = (int*)p;   p += (size_t)T_ * 2 * 4;
    float* top_w  = (float*)p; p += (size_t)T_ * 2 * 4;
    int*  slot_pos= (int*)p;   p += (size_t)T_ * 2 * 4;
    int*  slot_tok= (int*)p;   p += (size_t)TK_ * 4;
    int*  offsets = (int*)p;   p += 17 * 4;

    // all weight transposes in one launch; router fuses the x->bf16 convert
    k_transpose_all<<<dim3(30720), dim3(32, 8), 0, stream>>>(
        wgu, wdn, wsg, wsu, wsd, w_guT, w_dnT, w_sgT, w_suT, w_sdT);
    k_router<<<dim3(T_/4), 256, 0, stream>>>(x, rw, segw, logits, top_i, top_w, gate_s, xb);
    k_count<<<dim3(1), 256, 0, stream>>>(top_i, offsets);
    k_fillscan<<<dim3(E_), 256, 0, stream>>>(top_i, offsets, slot_tok, slot_pos);

    // phase A: all gate/up GEMMs in one launch (512-thread, 4 waves/SIMD)
    k_mlp1<<<dim3(4096 + 1024), 512, 0, stream>>>(xb, w_guT, w_sgT, w_suT, slot_tok, offsets, hiddenE, sh_hid);
    // phase B: all down GEMMs in one launch (512-thread, 4 waves/SIMD)
    k_mlp2<<<dim3(4096 + 256), 512, 0, stream>>>(hiddenE, sh_hid, w_dnT, w_sdT, offsets, gate_s, eo, out);

    // combine expert contributions into d_out
    k_combine<<<dim3(T_*256/256), 256, 0, stream>>>(out, eo, slot_pos, top_w);
}

// Round 17
// 183.479 us; speedup vs baseline: 2.2446x; 1.0665x over previous
//
#include <hip/hip_runtime.h>
#include <hip/hip_bf16.h>
#include <cstdint>

#define T_  4096
#define H_  1024
#define E_  16
#define MI_ 512
#define SI_ 2048
#define TK_ 8192   // T_ * K(=2)

typedef __bf16 bf16;
typedef bf16  bf16x8 __attribute__((ext_vector_type(8)));
typedef bf16  bf16x4 __attribute__((ext_vector_type(4)));
typedef float f32x4  __attribute__((ext_vector_type(4)));

// async global->LDS, 16B per lane. LDS dest = wave-uniform base + lane*16.
__device__ __forceinline__ void gload16(const bf16* g, bf16* lds) {
    __builtin_amdgcn_global_load_lds(
        (const __attribute__((address_space(1))) void*)(uintptr_t)(const void*)g,
        (__attribute__((address_space(3))) void*)(uintptr_t)(void*)lds,
        16, 0, 0);
}

// ---------------- all 5 weight transposes, one launch: fp32 [R][C] -> bf16 [C][R] ----------------
// 64x64 tiles, float4 loads (256B rows), bf16x4 stores (128B rows). LDS pad 65 (2-way = free).
__global__ __launch_bounds__(256) void k_transpose_all(
    const float* __restrict__ wgu, const float* __restrict__ wdn,
    const float* __restrict__ wsg, const float* __restrict__ wsu, const float* __restrict__ wsd,
    bf16* __restrict__ ogu, bf16* __restrict__ odn,
    bf16* __restrict__ osg, bf16* __restrict__ osu, bf16* __restrict__ osd)
{
    __shared__ float tile[64][65];
    int id = blockIdx.x;
    const float* src; bf16* dst; int R, C, bx, by;
    if (id < 4096) {               // wgu: 16 x [1024][1024] -> 16 x 256 tiles
        int s = id >> 8, r = id & 255;
        src = wgu + (size_t)s * 1048576; dst = ogu + (size_t)s * 1048576;
        R = 1024; C = 1024; bx = r & 15; by = r >> 4;
    } else if (id < 6144) {        // wdn: 16 x [512][1024] -> 16 x 128 tiles
        int k = id - 4096; int s = k >> 7, r = k & 127;
        src = wdn + (size_t)s * 524288; dst = odn + (size_t)s * 524288;
        R = 512; C = 1024; bx = r & 15; by = r >> 4;
    } else if (id < 6656) {        // wsg: [1024][2048] -> 512 tiles
        int r = id - 6144;
        src = wsg; dst = osg; R = 1024; C = 2048; bx = r & 31; by = r >> 5;
    } else if (id < 7168) {        // wsu: [1024][2048]
        int r = id - 6656;
        src = wsu; dst = osu; R = 1024; C = 2048; bx = r & 31; by = r >> 5;
    } else {                       // wsd: [2048][1024] -> 512 tiles (total 7680)
        int r = id - 7168;
        src = wsd; dst = osd; R = 2048; C = 1024; bx = r & 15; by = r >> 4;
    }
    int lane16 = threadIdx.x & 15, grp = threadIdx.x >> 4;
    #pragma unroll
    for (int i = 0; i < 4; i++) {
        int rr = i * 16 + grp;
        float4 v = *reinterpret_cast<const float4*>(
            &src[(size_t)(by * 64 + rr) * C + bx * 64 + lane16 * 4]);
        tile[rr][lane16 * 4 + 0] = v.x; tile[rr][lane16 * 4 + 1] = v.y;
        tile[rr][lane16 * 4 + 2] = v.z; tile[rr][lane16 * 4 + 3] = v.w;
    }
    __syncthreads();
    #pragma unroll
    for (int i = 0; i < 4; i++) {
        int cc = i * 16 + grp;              // orig col within tile
        bf16x4 o;
        #pragma unroll
        for (int j = 0; j < 4; j++) o[j] = (bf16)tile[lane16 * 4 + j][cc];
        *reinterpret_cast<bf16x4*>(
            &dst[(size_t)(bx * 64 + cc) * R + by * 64 + lane16 * 4]) = o;
    }
}

// ---------------- router + x->bf16 convert fused. NO atomics. ----------------
__global__ __launch_bounds__(256) void k_router(
    const float* __restrict__ x, const float* __restrict__ rw,
    const float* __restrict__ segw, float* __restrict__ logits_out,
    int* __restrict__ top_i, float* __restrict__ top_w,
    float* __restrict__ gate_scalar, bf16* __restrict__ xb)
{
    int wid = threadIdx.x >> 6, lane = threadIdx.x & 63;
    int t = blockIdx.x * 4 + wid;
    const float* xr = x + (size_t)t * H_;
    bf16* xbr = xb + (size_t)t * H_;
    float acc[E_];
    #pragma unroll
    for (int e = 0; e < E_; e++) acc[e] = 0.f;
    float accg = 0.f;
    for (int j = 0; j < H_ / 64; j++) {
        int h = j * 64 + lane;
        float xv = xr[h];
        xbr[h] = (bf16)xv;                    // fused convert
        const float4* wrow = reinterpret_cast<const float4*>(rw + (size_t)h * E_);
        #pragma unroll
        for (int q = 0; q < 4; q++) {
            float4 w4 = wrow[q];
            acc[q*4+0] += xv * w4.x; acc[q*4+1] += xv * w4.y;
            acc[q*4+2] += xv * w4.z; acc[q*4+3] += xv * w4.w;
        }
        accg += xv * segw[h];
    }
    #pragma unroll
    for (int off = 32; off >= 1; off >>= 1) {
        #pragma unroll
        for (int e = 0; e < E_; e++) acc[e] += __shfl_xor(acc[e], off);
        accg += __shfl_xor(accg, off);
    }
    if (lane == 0) {
        float* lo = logits_out + (size_t)t * E_;
        #pragma unroll
        for (int e = 0; e < E_; e++) lo[e] = acc[e];
        int i0 = 0; float l0 = acc[0];
        #pragma unroll
        for (int e = 1; e < E_; e++) if (acc[e] > l0) { l0 = acc[e]; i0 = e; }
        int i1 = -1; float l1 = -1e30f;
        #pragma unroll
        for (int e = 0; e < E_; e++) if (e != i0 && acc[e] > l1) { l1 = acc[e]; i1 = e; }
        float w0 = 1.f / (1.f + expf(l1 - l0));
        top_i[t*2] = i0; top_i[t*2+1] = i1;
        top_w[t*2] = w0; top_w[t*2+1] = 1.f - w0;
        gate_scalar[t] = 1.f / (1.f + expf(-accg));
    }
}

// ---------------- counts + offsets from top_i, single block ----------------
__global__ __launch_bounds__(256) void k_count(const int* __restrict__ top_i, int* __restrict__ offsets) {
    __shared__ int hist[256][17];
    int tid = threadIdx.x;
    #pragma unroll
    for (int e = 0; e < E_; e++) hist[tid][e] = 0;
    __syncthreads();
    const int* mine = top_i + tid * 32;
    #pragma unroll
    for (int j = 0; j < 32; j++) hist[tid][mine[j]]++;
    __syncthreads();
    if (tid < E_) {
        int s = 0;
        for (int r = 0; r < 256; r++) s += hist[r][tid];
        hist[0][tid] = s;
    }
    __syncthreads();
    if (tid == 0) {
        int s = 0;
        for (int e = 0; e < E_; e++) { offsets[e] = s; s += hist[0][e]; }
        offsets[E_] = s;
    }
}

// ---------------- deterministic slot assignment by rank, one block per expert ----------------
__global__ __launch_bounds__(256) void k_fillscan(
    const int* __restrict__ top_i, const int* __restrict__ offsets,
    int* __restrict__ slot_token, int* __restrict__ slot_pos)
{
    int e = blockIdx.x;
    int tid = threadIdx.x;
    int lane = tid & 63, w = tid >> 6;
    __shared__ int wsum[4];

    int t0 = tid * 16;
    unsigned f0 = 0, f1 = 0;
    int c = 0;
    #pragma unroll
    for (int j = 0; j < 16; j++) {
        int t = t0 + j;
        int a = top_i[t*2], b = top_i[t*2+1];
        if (a == e)      { f0 |= 1u << j; c++; }
        else if (b == e) { f1 |= 1u << j; c++; }
    }
    int incl = c;
    #pragma unroll
    for (int off = 1; off < 64; off <<= 1) {
        int v = __shfl_up(incl, off);
        if (lane >= off) incl += v;
    }
    if (lane == 63) wsum[w] = incl;
    __syncthreads();
    int wbase = 0;
    for (int i = 0; i < w; i++) wbase += wsum[i];
    int pos = offsets[e] + wbase + (incl - c);
    #pragma unroll
    for (int j = 0; j < 16; j++) {
        int t = t0 + j;
        if ((f0 >> j) & 1u)      { slot_token[pos] = t; slot_pos[t*2]   = pos; pos++; }
        else if ((f1 >> j) & 1u) { slot_token[pos] = t; slot_pos[t*2+1] = pos; pos++; }
    }
}

// ======= Phase A: gate/up GEMMs. 512 threads, 128x64-pair tile, BK=64, static dbuf. =======
// 8 waves (2m x 4n), wave = 64 rows x 16 paired cols; 4 waves/SIMD for drain cover.
__global__ __launch_bounds__(512) void k_mlp1(
    const bf16* __restrict__ xb, const bf16* __restrict__ wgu,
    const bf16* __restrict__ wsg, const bf16* __restrict__ wsu,
    const int* __restrict__ slot_token, const int* __restrict__ offsets,
    bf16* __restrict__ hiddenE, bf16* __restrict__ sh_hid)
{
    int bid = blockIdx.x;
    bool expert = bid < 4096;
    int nt, mt, base, cnt;
    const bf16 *Bg, *Bu;
    bf16* outp; int nout;
    if (expert) {
        int e = bid >> 8; int r = bid & 255; nt = r & 7; mt = r >> 3;
        base = offsets[e]; cnt = offsets[e+1] - base;
        if (mt * 128 >= cnt) return;
        const bf16* wb = wgu + (size_t)e * (2 * MI_) * H_;
        Bg = wb + (size_t)(nt * 64) * H_;
        Bu = wb + (size_t)(MI_ + nt * 64) * H_;
        outp = hiddenE; nout = MI_;
    } else {
        int r = bid - 4096; nt = r & 31; mt = r >> 5;
        base = 0; cnt = T_;
        Bg = wsg + (size_t)(nt * 64) * H_;
        Bu = wsu + (size_t)(nt * 64) * H_;
        outp = sh_hid; nout = SI_;
    }

    __shared__ __align__(16) bf16 As0[128 * 64], Bs0[128 * 64];
    __shared__ __align__(16) bf16 As1[128 * 64], Bs1[128 * 64];

    int tid = threadIdx.x, w = tid >> 6, l = tid & 63;
    int lrow8 = l >> 3;                       // row within 8-row staging group
    int col_off = ((l & 7) ^ lrow8) * 8;      // inverse-swizzled global chunk

    const bf16* asrc[2];
    const bf16* bsrc[2];
    #pragma unroll
    for (int g = 0; g < 2; g++) {
        int rt = g * 64 + w * 8 + lrow8;      // row within 128-tile
        int s = mt * 128 + rt; if (s >= cnt) s = cnt - 1;
        asrc[g] = (expert ? xb + (size_t)slot_token[base + s] * H_
                          : xb + (size_t)s * H_) + col_off;
        int half = (rt >> 4) & 1;             // 16-row interleave: 0=gate, 1=up
        int gcol = ((rt >> 5) << 4) | (rt & 15);
        bsrc[g] = (half ? Bu : Bg) + (size_t)gcol * H_ + col_off;
    }

    int lr = l & 15, kq = l >> 4;
    int wm = w & 1, wn = w >> 1;              // 2m x 4n wave grid
    f32x4 acc[4][2];
    #pragma unroll
    for (int mi = 0; mi < 4; mi++)
        #pragma unroll
        for (int ni = 0; ni < 2; ni++) acc[mi][ni] = (f32x4){0.f, 0.f, 0.f, 0.f};

    auto STAGE = [&](bf16* Ad, bf16* Bd, int k0) {
        #pragma unroll
        for (int g = 0; g < 2; g++) {
            gload16(asrc[g] + k0, Ad + (g * 64 + w * 8) * 64);
            gload16(bsrc[g] + k0, Bd + (g * 64 + w * 8) * 64);
        }
    };
    auto COMPUTE = [&](const bf16* Ab, const bf16* Bb) {
        #pragma unroll
        for (int ks = 0; ks < 2; ks++) {
            int cl = ((ks * 4 + kq) ^ (lr & 7)) * 8;   // swizzled read chunk
            bf16x8 af[4], bfr[2];
            #pragma unroll
            for (int mi = 0; mi < 4; mi++)
                af[mi] = *reinterpret_cast<const bf16x8*>(&Ab[(wm * 64 + mi * 16 + lr) * 64 + cl]);
            #pragma unroll
            for (int ni = 0; ni < 2; ni++)
                bfr[ni] = *reinterpret_cast<const bf16x8*>(&Bb[(wn * 32 + ni * 16 + lr) * 64 + cl]);
            #pragma unroll
            for (int mi = 0; mi < 4; mi++)
                #pragma unroll
                for (int ni = 0; ni < 2; ni++)
                    acc[mi][ni] = __builtin_amdgcn_mfma_f32_16x16x32_bf16(af[mi], bfr[ni], acc[mi][ni], 0, 0, 0);
        }
    };

    STAGE(As0, Bs0, 0);
    __syncthreads();
    for (int k0 = 0; k0 < H_; k0 += 128) {
        STAGE(As1, Bs1, k0 + 64);     // flies during COMPUTE(As0)
        COMPUTE(As0, Bs0);
        __syncthreads();
        if (k0 + 128 < H_) STAGE(As0, Bs0, k0 + 128);  // flies during COMPUTE(As1)
        COMPUTE(As1, Bs1);
        __syncthreads();
    }

    // epilogue: gate=acc[mi][0], up=acc[mi][1]; col = nt*64 + wn*16 + lr
    #pragma unroll
    for (int mi = 0; mi < 4; mi++)
        #pragma unroll
        for (int r = 0; r < 4; r++) {
            int row = mt * 128 + wm * 64 + mi * 16 + kq * 4 + r;
            if (row < cnt) {
                int col = nt * 64 + wn * 16 + lr;
                float g = acc[mi][0][r], u = acc[mi][1][r];
                float hv = u * (g / (1.f + expf(-g)));
                outp[(size_t)(base + row) * nout + col] = (bf16)hv;
            }
        }
}

// ======= Phase B: down GEMMs. 512 threads, 128x128 tile, BK=64, static dbuf. =======
// LPT ordering: shared (K=2048, longest) dispatches FIRST (bid<256), experts fill behind.
__global__ __launch_bounds__(512) void k_mlp2(
    const bf16* __restrict__ hiddenE, const bf16* __restrict__ sh_hid,
    const bf16* __restrict__ wdn, const bf16* __restrict__ wsd,
    const int* __restrict__ offsets, const float* __restrict__ gate_s,
    bf16* __restrict__ eo, float* __restrict__ out)
{
    int bid = blockIdx.x;
    bool expert = bid >= 256;
    int nt, mt, base, cnt, KD;
    const bf16 *Ab, *B0;
    if (expert) {
        int rr = bid - 256;
        int e = rr >> 8; int r = rr & 255; nt = r & 7; mt = r >> 3;
        base = offsets[e]; cnt = offsets[e+1] - base;
        if (mt * 128 >= cnt) return;
        KD = MI_;
        Ab = hiddenE;
        B0 = wdn + (size_t)e * H_ * MI_ + (size_t)(nt * 128) * MI_;
    } else {
        nt = bid & 7; mt = bid >> 3;
        base = 0; cnt = T_; KD = SI_;
        Ab = sh_hid;
        B0 = wsd + (size_t)(nt * 128) * SI_;
    }

    __shared__ __align__(16) bf16 As0[128 * 64], Bs0[128 * 64];
    __shared__ __align__(16) bf16 As1[128 * 64], Bs1[128 * 64];

    int tid = threadIdx.x, w = tid >> 6, l = tid & 63;
    int lrow8 = l >> 3;
    int col_off = ((l & 7) ^ lrow8) * 8;

    const bf16* asrc[2];
    const bf16* bsrc[2];
    #pragma unroll
    for (int g = 0; g < 2; g++) {
        int rt = g * 64 + w * 8 + lrow8;
        int s = mt * 128 + rt; if (s >= cnt) s = cnt - 1;
        asrc[g] = Ab + (size_t)(base + s) * KD + col_off;
        bsrc[g] = B0 + (size_t)rt * KD + col_off;
    }

    int lr = l & 15, kq = l >> 4;
    int wm = w & 1, wn = w >> 1;              // 2m x 4n wave grid
    f32x4 acc[4][2];
    #pragma unroll
    for (int mi = 0; mi < 4; mi++)
        #pragma unroll
        for (int ni = 0; ni < 2; ni++) acc[mi][ni] = (f32x4){0.f, 0.f, 0.f, 0.f};

    auto STAGE = [&](bf16* Ad, bf16* Bd, int k0) {
        #pragma unroll
        for (int g = 0; g < 2; g++) {
            gload16(asrc[g] + k0, Ad + (g * 64 + w * 8) * 64);
            gload16(bsrc[g] + k0, Bd + (g * 64 + w * 8) * 64);
        }
    };
    auto COMPUTE = [&](const bf16* Abuf, const bf16* Bbuf) {
        #pragma unroll
        for (int ks = 0; ks < 2; ks++) {
            int cl = ((ks * 4 + kq) ^ (lr & 7)) * 8;
            bf16x8 af[4], bfr[2];
            #pragma unroll
            for (int mi = 0; mi < 4; mi++)
                af[mi] = *reinterpret_cast<const bf16x8*>(&Abuf[(wm * 64 + mi * 16 + lr) * 64 + cl]);
            #pragma unroll
            for (int ni = 0; ni < 2; ni++)
                bfr[ni] = *reinterpret_cast<const bf16x8*>(&Bbuf[(wn * 32 + ni * 16 + lr) * 64 + cl]);
            #pragma unroll
            for (int mi = 0; mi < 4; mi++)
                #pragma unroll
                for (int ni = 0; ni < 2; ni++)
                    acc[mi][ni] = __builtin_amdgcn_mfma_f32_16x16x32_bf16(af[mi], bfr[ni], acc[mi][ni], 0, 0, 0);
        }
    };

    STAGE(As0, Bs0, 0);
    __syncthreads();
    for (int k0 = 0; k0 < KD; k0 += 128) {
        STAGE(As1, Bs1, k0 + 64);
        COMPUTE(As0, Bs0);
        __syncthreads();
        if (k0 + 128 < KD) STAGE(As0, Bs0, k0 + 128);
        COMPUTE(As1, Bs1);
        __syncthreads();
    }

    #pragma unroll
    for (int mi = 0; mi < 4; mi++)
        #pragma unroll
        for (int ni = 0; ni < 2; ni++)
            #pragma unroll
            for (int r = 0; r < 4; r++) {
                int row = mt * 128 + wm * 64 + mi * 16 + kq * 4 + r;
                if (row < cnt) {
                    int col = nt * 128 + wn * 32 + ni * 16 + lr;
                    float v = acc[mi][ni][r];
                    if (expert) eo[(size_t)(base + row) * H_ + col] = (bf16)v;
                    else        out[(size_t)row * H_ + col] = gate_s[row] * v;
                }
            }
}

// ---------------- combine: out += w0*eo[s0] + w1*eo[s1] ----------------
__global__ void k_combine(float* __restrict__ out, const bf16* __restrict__ eo,
                          const int* __restrict__ slot_pos, const float* __restrict__ top_w)
{
    int i = blockIdx.x * blockDim.x + threadIdx.x;
    int t = i >> 8;
    int q = (i & 255) * 4;
    int s0 = slot_pos[t*2], s1 = slot_pos[t*2+1];
    float w0 = top_w[t*2], w1 = top_w[t*2+1];
    bf16x4 e0 = *reinterpret_cast<const bf16x4*>(eo + (size_t)s0 * H_ + q);
    bf16x4 e1 = *reinterpret_cast<const bf16x4*>(eo + (size_t)s1 * H_ + q);
    float4* op = reinterpret_cast<float4*>(out) + i;
    float4 so = *op;
    float4 r;
    r.x = so.x + w0 * (float)e0[0] + w1 * (float)e1[0];
    r.y = so.y + w0 * (float)e0[1] + w1 * (float)e1[1];
    r.z = so.z + w0 * (float)e0[2] + w1 * (float)e1[2];
    r.w = so.w + w0 * (float)e0[3] + w1 * (float)e1[3];
    *op = r;
}

extern "C" void kernel_launch(void* const* d_in, const int* in_sizes, int n_in,
                              void* d_out, int out_size, void* d_ws, size_t ws_size,
                              hipStream_t stream) {
    const float* x    = (const float*)d_in[0];
    const float* rw   = (const float*)d_in[1];
    const float* wgu  = (const float*)d_in[2];
    const float* wdn  = (const float*)d_in[3];
    const float* wsg  = (const float*)d_in[4];
    const float* wsu  = (const float*)d_in[5];
    const float* wsd  = (const float*)d_in[6];
    const float* segw = (const float*)d_in[7];
    float* out    = (float*)d_out;
    float* logits = (float*)d_out + (size_t)T_ * H_;

    char* p = (char*)d_ws;
    bf16* xb      = (bf16*)p;  p += (size_t)T_ * H_ * 2;
    bf16* w_guT   = (bf16*)p;  p += (size_t)E_ * H_ * (2*MI_) * 2;
    bf16* w_dnT   = (bf16*)p;  p += (size_t)E_ * MI_ * H_ * 2;
    bf16* w_sgT   = (bf16*)p;  p += (size_t)H_ * SI_ * 2;
    bf16* w_suT   = (bf16*)p;  p += (size_t)H_ * SI_ * 2;
    bf16* w_sdT   = (bf16*)p;  p += (size_t)SI_ * H_ * 2;
    bf16* hiddenE = (bf16*)p;  p += (size_t)TK_ * MI_ * 2;
    bf16* sh_hid  = (bf16*)p;  p += (size_t)T_ * SI_ * 2;
    bf16* eo      = (bf16*)p;  p += (size_t)TK_ * H_ * 2;
    float* gate_s = (float*)p; p += (size_t)T_ * 4;
    int*  top_i   = (int*)p;   p += (size_t)T_ * 2 * 4;
    float* top_w  = (float*)p; p += (size_t)T_ * 2 * 4;
    int*  slot_pos= (int*)p;   p += (size_t)T_ * 2 * 4;
    int*  slot_tok= (int*)p;   p += (size_t)TK_ * 4;
    int*  offsets = (int*)p;   p += 17 * 4;

    // all weight transposes in one launch (vectorized 64x64); router fuses x->bf16 convert
    k_transpose_all<<<dim3(7680), 256, 0, stream>>>(
        wgu, wdn, wsg, wsu, wsd, w_guT, w_dnT, w_sgT, w_suT, w_sdT);
    k_router<<<dim3(T_/4), 256, 0, stream>>>(x, rw, segw, logits, top_i, top_w, gate_s, xb);
    k_count<<<dim3(1), 256, 0, stream>>>(top_i, offsets);
    k_fillscan<<<dim3(E_), 256, 0, stream>>>(top_i, offsets, slot_tok, slot_pos);

    // phase A: all gate/up GEMMs (512-thread, 4 waves/SIMD)
    k_mlp1<<<dim3(4096 + 1024), 512, 0, stream>>>(xb, w_guT, w_sgT, w_suT, slot_tok, offsets, hiddenE, sh_hid);
    // phase B: all down GEMMs (shared-first LPT ordering)
    k_mlp2<<<dim3(4096 + 256), 512, 0, stream>>>(hiddenE, sh_hid, w_dnT, w_sdT, offsets, gate_s, eo, out);

    // combine expert contributions into d_out
    k_combine<<<dim3(T_*256/256), 256, 0, stream>>>(out, eo, slot_pos, top_w);
}